// Round 10
// baseline (1575.946 us; speedup 1.0000x reference)
//
#include <hip/hip_runtime.h>
#include <hip/hip_bf16.h>
#include <stdint.h>

#define S_LEN 2048
#define D_MODEL 2048
#define NH 16
#define HD_DIM 128
#define BATCH 4

typedef unsigned short u16;
typedef unsigned int u32;
typedef short s16x8 __attribute__((ext_vector_type(8)));
typedef float f32x4 __attribute__((ext_vector_type(4)));

__device__ __forceinline__ u16 f2b(float f) {
    union { float f; u32 u; } v; v.f = f;
    u32 r = v.u + 0x7FFFu + ((v.u >> 16) & 1u);
    return (u16)(r >> 16);
}

__device__ __forceinline__ u32 cvtpk(float lo, float hi) {
    u32 r;
    asm volatile("v_cvt_pk_bf16_f32 %0, %1, %2" : "=v"(r) : "v"(lo), "v"(hi));
    return r;
}

#define BAR()   asm volatile("s_barrier" ::: "memory")
#define LGKM0() asm volatile("s_waitcnt lgkmcnt(0)" ::: "memory")
#define VMW(n)  asm volatile("s_waitcnt vmcnt(" #n ")" ::: "memory")

// ---------------- fp32 -> bf16 conversion (weights + activations) ----------------
__global__ __launch_bounds__(256) void cvt_bf16(const float* __restrict__ in,
                                                u16* __restrict__ out, int n8) {
    int i = blockIdx.x * 256 + threadIdx.x;
    if (i >= n8) return;
    const float4* p = reinterpret_cast<const float4*>(in) + (size_t)i * 2;
    float4 a = p[0], b = p[1];
    s16x8 o;
    o[0] = (short)f2b(a.x); o[1] = (short)f2b(a.y);
    o[2] = (short)f2b(a.z); o[3] = (short)f2b(a.w);
    o[4] = (short)f2b(b.x); o[5] = (short)f2b(b.y);
    o[6] = (short)f2b(b.z); o[7] = (short)f2b(b.w);
    *(reinterpret_cast<s16x8*>(out) + i) = o;
}

// ---------------- 256x256 8-phase NT GEMM: C = alpha * A[M,K] @ B[N,K]^T ----------------
// OUT_MODE: 0 = bf16 row-major C[M,N]; 1 = f32 row-major.
template<int OUT_MODE>
__global__ __launch_bounds__(512, 1) void gemm256(const u16* __restrict__ Ab,
                                                  const u16* __restrict__ Bw,
                                                  void* __restrict__ Cv,
                                                  int M, int N, int K, float alpha) {
    __shared__ u16 lds[2][2][256 * 64];
    const int t = threadIdx.x, lane = t & 63, w = t >> 6;
    const int wm = w >> 2, wn = w & 3;
    const int lr = lane & 15, lk = lane >> 4;
    const int NT = K >> 6;

    // bijective XCD swizzle (gridDim.x % 8 == 0 for all launches here)
    const int ntile = N >> 8;
    int flat = blockIdx.x;
    int cpx = gridDim.x >> 3;
    int rmap = (flat & 7) * cpx + (flat >> 3);
    const int m0 = (rmap / ntile) * 256, n0 = (rmap % ntile) * 256;

    // staging constants: thread covers row q*64 + (t>>3), position chunk t&7
    const int srow = t >> 3;
    const int spos = t & 7;
    const int scon = spos ^ (srow & 7);   // content chunk (pre-swizzled source)

    auto stage = [&](const u16* gbase, int grow0, int ldsT, int buf, int q, int kt) {
        const u16* src = gbase + (size_t)(grow0 + q * 64 + srow) * K + kt * 64 + scon * 8;
        u16* dst = &lds[buf][ldsT][(q * 64 + srow) * 64 + spos * 8];
        __builtin_amdgcn_global_load_lds(
            (const __attribute__((address_space(1))) void*)src,
            (__attribute__((address_space(3))) void*)dst, 16, 0, 0);
    };

    f32x4 acc[8][4];
#pragma unroll
    for (int i = 0; i < 8; ++i)
#pragma unroll
        for (int j = 0; j < 4; ++j) acc[i][j] = {0.f, 0.f, 0.f, 0.f};

    s16x8 a[4][2], b[4][2];

    // prologue: tile 0, order BQ0-3, AQ0, AQ2, AQ1, AQ3 (A-upper last)
    stage(Bw, n0, 1, 0, 0, 0);
    stage(Bw, n0, 1, 0, 1, 0);
    stage(Bw, n0, 1, 0, 2, 0);
    stage(Bw, n0, 1, 0, 3, 0);
    stage(Ab, m0, 0, 0, 0, 0);
    stage(Ab, m0, 0, 0, 2, 0);
    stage(Ab, m0, 0, 0, 1, 0);
    stage(Ab, m0, 0, 0, 3, 0);
    VMW(2);
    BAR();

#define LDFRAG(base, row, kk) \
    (*(const s16x8*)((base) + (row) * 64 + ((((kk) * 4 + lk) ^ (lr & 7)) << 3)))

#define QUAD(mh, nh)                                                                   \
    __builtin_amdgcn_s_setprio(1);                                                     \
    _Pragma("unroll")                                                                  \
    for (int mf = 0; mf < 4; ++mf)                                                     \
        _Pragma("unroll")                                                              \
        for (int nf = 0; nf < 2; ++nf)                                                 \
            _Pragma("unroll")                                                          \
            for (int kk = 0; kk < 2; ++kk)                                             \
                acc[(mh) * 4 + mf][(nh) * 2 + nf] = __builtin_amdgcn_mfma_f32_16x16x32_bf16( \
                    a[mf][kk], b[(nh) * 2 + nf][kk], acc[(mh) * 4 + mf][(nh) * 2 + nf], 0, 0, 0); \
    __builtin_amdgcn_s_setprio(0);

    for (int kt = 0; kt < NT; ++kt) {
        const int buf = kt & 1;
        const u16* la = &lds[buf][0][0];
        const u16* lb = &lds[buf][1][0];
        const int nx = kt + 1;
        const bool st = nx < NT;

        // ---- phase 0: quadrant (0,0) ----
#pragma unroll
        for (int mf = 0; mf < 4; ++mf)
#pragma unroll
            for (int kk = 0; kk < 2; ++kk)
                a[mf][kk] = LDFRAG(la, wm * 128 + mf * 16 + lr, kk);
#pragma unroll
        for (int nf = 0; nf < 2; ++nf)
#pragma unroll
            for (int kk = 0; kk < 2; ++kk)
                b[nf][kk] = LDFRAG(lb, wn * 64 + nf * 16 + lr, kk);
        if (st) { stage(Bw, n0, 1, buf ^ 1, 0, nx); stage(Bw, n0, 1, buf ^ 1, 1, nx); }
        BAR();
        LGKM0();
        QUAD(0, 0);
        BAR();

        // ---- phase 1: quadrant (0,1) ----
#pragma unroll
        for (int nf = 2; nf < 4; ++nf)
#pragma unroll
            for (int kk = 0; kk < 2; ++kk)
                b[nf][kk] = LDFRAG(lb, wn * 64 + nf * 16 + lr, kk);
        if (st) { stage(Bw, n0, 1, buf ^ 1, 2, nx); stage(Bw, n0, 1, buf ^ 1, 3, nx); }
        BAR();
        LGKM0();
        QUAD(0, 1);
        if (kt == NT - 1) { VMW(0); } else { VMW(4); }   // current tile's A-upper landed
        BAR();

        // ---- phase 2: quadrant (1,0) ----
#pragma unroll
        for (int mf = 0; mf < 4; ++mf)
#pragma unroll
            for (int kk = 0; kk < 2; ++kk)
                a[mf][kk] = LDFRAG(la, wm * 128 + 64 + mf * 16 + lr, kk);
        if (st) { stage(Ab, m0, 0, buf ^ 1, 0, nx); stage(Ab, m0, 0, buf ^ 1, 2, nx); }
        BAR();
        LGKM0();
        QUAD(1, 0);
        BAR();

        // ---- phase 3: quadrant (1,1) ----
        if (st) { stage(Ab, m0, 0, buf ^ 1, 1, nx); stage(Ab, m0, 0, buf ^ 1, 3, nx); }
        BAR();
        QUAD(1, 1);
        VMW(2);   // next tile's first 6 quarters landed
        BAR();
    }

    // epilogue: C layout col = lr, row = lk*4 + reg
#pragma unroll
    for (int i = 0; i < 8; ++i)
#pragma unroll
        for (int j = 0; j < 4; ++j) {
            int r0 = m0 + wm * 128 + (i >> 2) * 64 + (i & 3) * 16 + lk * 4;
            int c0 = n0 + wn * 64 + j * 16 + lr;
            if constexpr (OUT_MODE == 1) {
                float* C = (float*)Cv;
#pragma unroll
                for (int r = 0; r < 4; ++r) C[(size_t)(r0 + r) * N + c0] = acc[i][j][r] * alpha;
            } else {
                u16* C = (u16*)Cv;
#pragma unroll
                for (int r = 0; r < 4; ++r) C[(size_t)(r0 + r) * N + c0] = f2b(acc[i][j][r] * alpha);
            }
        }
}

// ---------------- flash attention ----------------
// Round-9 proven protocol (V dbuf in LDS via shfl-transpose, K dbuf via global_load_lds,
// ONE __syncthreads per tile, defer-max, mask/kpad reg-prefetch), widened to
// 8 waves / 512 threads / 256 q-rows per block (grid 512):
//  - waves/SIMD 2 -> 4 (2 blocks/CU x 8 waves; LDS still 64 KiB, VGPR capped 128)
//  - K/V staged once per 256 q-rows instead of 128 (staging work + K/V traffic halve)
// Per-wave compute code is UNCHANGED; only staging index math is reworked.
__global__ __launch_bounds__(512, 4) void attn_kernel(
    const u16* __restrict__ Qh, const u16* __restrict__ Kh, const u16* __restrict__ Vh,
    const float* __restrict__ mask, const float* __restrict__ kpad,
    u16* __restrict__ Comb) {
    __shared__ u16 Ks[2][64 * 128];
    __shared__ u16 Vt[2][128 * 64];

    const int t = threadIdx.x, lane = t & 63, w = t >> 6;   // w: 0..7
    const int lr = lane & 15, lk = lane >> 4;

    const int g = blockIdx.x;
    const int rm = (g & 7) * 64 + (g >> 3);      // 512 % 8 == 0: bijective
    const int qb = rm & 7, h = (rm >> 3) & 15, b = rm >> 7;  // qb fast (L3-friendly)
    const int q0w = qb * 256 + w * 32;
    const size_t rowBase = (size_t)b * S_LEN;
    const u16* Kb = Kh + rowBase * D_MODEL + h * HD_DIM;
    const u16* Vb = Vh + rowBase * D_MODEL + h * HD_DIM;

    // Q fragments (B operand): q = q0w + qi*16 + lr, d = dc*32 + lk*8 + j. (scale pre-folded)
    s16x8 qf[2][4];
#pragma unroll
    for (int qi = 0; qi < 2; ++qi)
#pragma unroll
        for (int dc = 0; dc < 4; ++dc)
            qf[qi][dc] = *(const s16x8*)(Qh + (rowBase + q0w + qi * 16 + lr) * D_MODEL +
                                         h * HD_DIM + dc * 32 + lk * 8);

    f32x4 o[2][8];
#pragma unroll
    for (int qi = 0; qi < 2; ++qi)
#pragma unroll
        for (int dt = 0; dt < 8; ++dt) o[qi][dt] = {0.f, 0.f, 0.f, 0.f};
    float m_[2] = {-3e38f, -3e38f}, l_[2] = {0.f, 0.f};

    // K staging (512 threads, 2 passes of 32 rows):
    // LDS row R = p*32 + (t>>4), position chunk t&15, content chunk = (t&15) ^ (R&7)
    const int ksub = t >> 4;                          // 0..31
    const int kchunk = (t & 15) ^ (ksub & 7);         // pre-swizzled global chunk
    // V staging (512 threads, one pass: row = t>>3 covers all 64 kv rows)
    const int vrow = t >> 3;                          // 0..63
    const int vc0 = (t & 7) * 16;
    const int vodd = vrow & 1;
    const int vp = t >> 4;                            // kv-pair 0..31

    s16x8 va0, va1;

    auto stageK = [&](int kv0, int nb) {
#pragma unroll
        for (int p = 0; p < 2; ++p) {
            const u16* src = Kb + (size_t)(kv0 + p * 32 + ksub) * D_MODEL + kchunk * 8;
            __builtin_amdgcn_global_load_lds(
                (const __attribute__((address_space(1))) void*)src,
                (__attribute__((address_space(3))) void*)(&Ks[nb][p * 4096 + t * 8]), 16, 0, 0);
        }
    };
    auto loadV = [&](int kv0) {
        const u16* p0 = Vb + (size_t)(kv0 + vrow) * D_MODEL + vc0;
        va0 = *(const s16x8*)p0;
        va1 = *(const s16x8*)(p0 + 8);
    };
    auto writeV = [&](int nb) {
        union VU { s16x8 v[2]; u32 uw[8]; u16 us[16]; };
        VU A;
        A.v[0] = va0; A.v[1] = va1;
        u32 ra[4];
#pragma unroll
        for (int i = 0; i < 4; ++i)
            ra[i] = (u32)__shfl_xor((int)(vodd ? A.uw[i] : A.uw[i + 4]), 8, 64);
#pragma unroll
        for (int e = 0; e < 8; ++e) {
            int d = vc0 + vodd * 8 + e;
            int swz = ((d >> 4) ^ (d & 7)) & 7;
            u16 rau = (u16)((ra[e >> 1] >> ((e & 1) * 16)) & 0xffff);
            u16 lo1, hi1;
            if (vodd) { lo1 = rau; hi1 = A.us[8 + e]; }
            else      { lo1 = A.us[e]; hi1 = rau; }
            int c1 = (vp >> 2) ^ swz;
            *(u32*)(&Vt[nb][d * 64 + c1 * 8 + (vp & 3) * 2]) = (u32)lo1 | ((u32)hi1 << 16);
        }
    };

    // mask/kpad register prefetch (one tile ahead)
    f32x4 mreg[2][4], kreg[4];
    auto loadMask = [&](int kv0) {
#pragma unroll
        for (int qi = 0; qi < 2; ++qi) {
            const float* mrow = mask + (size_t)(q0w + qi * 16 + lr) * S_LEN + kv0;
#pragma unroll
            for (int kt = 0; kt < 4; ++kt)
                mreg[qi][kt] = *(const f32x4*)(mrow + kt * 16 + lk * 4);
        }
#pragma unroll
        for (int kt = 0; kt < 4; ++kt)
            kreg[kt] = *(const f32x4*)(kpad + b * S_LEN + kv0 + kt * 16 + lk * 4);
    };

    // prologue: stage tile 0
    stageK(0, 0);
    loadV(0);
    writeV(0);
    loadMask(0);
    __syncthreads();

    const int srcA = ((lk & 1) * 32) + lr;   // lane holding lk' = (lk&1)*2
    const int srcB = srcA + 16;

    for (int i = 0; i < 32; ++i) {
        const int cur = i & 1;
        const u16* ks = &Ks[cur][0];
        const u16* vt = &Vt[cur][0];
        const int kv0 = i * 64;

        if (i < 31) { stageK(kv0 + 64, cur ^ 1); loadV(kv0 + 64); }

        // QK^T (swapped): sc[qi][kt]: lane holds S[kv=kt*16+lk*4+r][q=qi*16+lr]
        f32x4 sc[2][4];
#pragma unroll
        for (int qi = 0; qi < 2; ++qi)
#pragma unroll
            for (int kt = 0; kt < 4; ++kt) sc[qi][kt] = {0.f, 0.f, 0.f, 0.f};
        __builtin_amdgcn_s_setprio(1);
#pragma unroll
        for (int kt = 0; kt < 4; ++kt) {
            s16x8 kf[4];
#pragma unroll
            for (int dc = 0; dc < 4; ++dc)
                kf[dc] = *(const s16x8*)(&ks[(kt * 16 + lr) * 128 +
                                             (((dc * 4 + lk) ^ (lr & 7)) << 3)]);
#pragma unroll
            for (int dc = 0; dc < 4; ++dc) {
                sc[0][kt] = __builtin_amdgcn_mfma_f32_16x16x32_bf16(kf[dc], qf[0][dc], sc[0][kt], 0, 0, 0);
                sc[1][kt] = __builtin_amdgcn_mfma_f32_16x16x32_bf16(kf[dc], qf[1][dc], sc[1][kt], 0, 0, 0);
            }
        }
        __builtin_amdgcn_s_setprio(0);

        // masks (prefetched regs) + online softmax (per-lane row-local: q = lr)
        u32 lo[2][4], hi[2][4];
#pragma unroll
        for (int qi = 0; qi < 2; ++qi) {
            float s[16];
            float mx = -3e38f;
#pragma unroll
            for (int kt = 0; kt < 4; ++kt)
#pragma unroll
                for (int r = 0; r < 4; ++r) {
                    float v = sc[qi][kt][r] + mreg[qi][kt][r] + kreg[kt][r];
                    s[kt * 4 + r] = v;
                    mx = fmaxf(mx, v);
                }
            mx = fmaxf(mx, __shfl_xor(mx, 16, 64));
            mx = fmaxf(mx, __shfl_xor(mx, 32, 64));
            // defer-max (T13, THR=8): rescale only when the running max grows
            if (__any(mx > m_[qi] + 8.0f)) {
                float mn = fmaxf(m_[qi], mx);
                float fs = __expf(m_[qi] - mn);
                m_[qi] = mn;
                l_[qi] *= fs;
#pragma unroll
                for (int r = 0; r < 4; ++r) {
                    float fsb = __shfl(fs, (lane & 48) | (lk * 4 + r), 64);
#pragma unroll
                    for (int dt = 0; dt < 8; ++dt) o[qi][dt][r] *= fsb;
                }
            }
            float ls = 0.f;
#pragma unroll
            for (int e = 0; e < 16; ++e) { s[e] = __expf(s[e] - m_[qi]); ls += s[e]; }
            ls += __shfl_xor(ls, 16, 64);
            ls += __shfl_xor(ls, 32, 64);
            l_[qi] += ls;
#pragma unroll
            for (int kt = 0; kt < 4; ++kt) {
                lo[qi][kt] = cvtpk(s[kt * 4 + 0], s[kt * 4 + 1]);
                hi[qi][kt] = cvtpk(s[kt * 4 + 2], s[kt * 4 + 3]);
            }
        }

        // prefetch next tile's mask/kpad (regs free after s[] computed above)
        if (i < 31) loadMask(kv0 + 64);

        // redistribute P (C-layout) -> A-frag in-register
        s16x8 pf[2][2];
        const bool sel = (lk >> 1) & 1;
#pragma unroll
        for (int qi = 0; qi < 2; ++qi)
#pragma unroll
            for (int hh = 0; hh < 2; ++hh) {
                u32 w0a = (u32)__shfl((int)lo[qi][2 * hh], srcA, 64);
                u32 w0b = (u32)__shfl((int)lo[qi][2 * hh + 1], srcA, 64);
                u32 w1a = (u32)__shfl((int)hi[qi][2 * hh], srcA, 64);
                u32 w1b = (u32)__shfl((int)hi[qi][2 * hh + 1], srcA, 64);
                u32 w2a = (u32)__shfl((int)lo[qi][2 * hh], srcB, 64);
                u32 w2b = (u32)__shfl((int)lo[qi][2 * hh + 1], srcB, 64);
                u32 w3a = (u32)__shfl((int)hi[qi][2 * hh], srcB, 64);
                u32 w3b = (u32)__shfl((int)hi[qi][2 * hh + 1], srcB, 64);
                union { s16x8 v; u32 u[4]; } P;
                P.u[0] = sel ? w0b : w0a;
                P.u[1] = sel ? w1b : w1a;
                P.u[2] = sel ? w2b : w2a;
                P.u[3] = sel ? w3b : w3a;
                pf[qi][hh] = P.v;
            }

        // PV: o[qi][dt] += P[16x64] @ V[64x16]
        __builtin_amdgcn_s_setprio(1);
#pragma unroll
        for (int dt = 0; dt < 8; ++dt) {
            int swz = dt ^ (lr & 7);
            s16x8 vf0 = *(const s16x8*)(&vt[(dt * 16 + lr) * 64 + ((lk ^ swz) << 3)]);
            s16x8 vf1 = *(const s16x8*)(&vt[(dt * 16 + lr) * 64 + (((4 + lk) ^ swz) << 3)]);
            o[0][dt] = __builtin_amdgcn_mfma_f32_16x16x32_bf16(pf[0][0], vf0, o[0][dt], 0, 0, 0);
            o[1][dt] = __builtin_amdgcn_mfma_f32_16x16x32_bf16(pf[1][0], vf0, o[1][dt], 0, 0, 0);
            o[0][dt] = __builtin_amdgcn_mfma_f32_16x16x32_bf16(pf[0][1], vf1, o[0][dt], 0, 0, 0);
            o[1][dt] = __builtin_amdgcn_mfma_f32_16x16x32_bf16(pf[1][1], vf1, o[1][dt], 0, 0, 0);
        }
        __builtin_amdgcn_s_setprio(0);

        if (i < 31) writeV(cur ^ 1);
        __syncthreads();
    }

    // epilogue: O = o / l; o C-layout: q = qi*16 + lk*4 + r, d = dt*16 + lr
#pragma unroll
    for (int qi = 0; qi < 2; ++qi)
#pragma unroll
        for (int r = 0; r < 4; ++r) {
            float lb = __shfl(l_[qi], (lane & 48) | (lk * 4 + r), 64);
            float inv = 1.0f / lb;
            size_t row = rowBase + q0w + qi * 16 + lk * 4 + r;
            u16* dst = Comb + row * D_MODEL + h * HD_DIM + lr;
#pragma unroll
            for (int dt = 0; dt < 8; ++dt) dst[dt * 16] = f2b(o[qi][dt][r] * inv);
        }
}

extern "C" void kernel_launch(void* const* d_in, const int* in_sizes, int n_in,
                              void* d_out, int out_size, void* d_ws, size_t ws_size,
                              hipStream_t stream) {
    const float* q    = (const float*)d_in[0];
    const float* k    = (const float*)d_in[1];
    const float* v    = (const float*)d_in[2];
    const float* mask = (const float*)d_in[3];
    const float* kpad = (const float*)d_in[4];
    const float* wq   = (const float*)d_in[5];
    const float* wk   = (const float*)d_in[6];
    const float* wv   = (const float*)d_in[7];
    const float* wo   = (const float*)d_in[8];
    float* out = (float*)d_out;

    u16* wqb  = (u16*)d_ws;                 // 2048*2048 bf16 each
    u16* wkb  = wqb + 4194304;
    u16* wvb  = wkb + 4194304;
    u16* wob  = wvb + 4194304;
    u16* qh   = wob + 4194304;              // 8192*2048 bf16 each
    u16* kh   = qh + 16777216;
    u16* vh   = kh + 16777216;
    u16* comb = vh + 16777216;              // doubles as activation bf16 staging
    // total: 160 MB

    const float scale = 0.08838834764831845f;  // 1/sqrt(128), folded into Q projection

    {
        int n8 = 4194304 / 8;
        dim3 gw((n8 + 255) / 256);
        cvt_bf16<<<gw, 256, 0, stream>>>(wq, wqb, n8);
        cvt_bf16<<<gw, 256, 0, stream>>>(wk, wkb, n8);
        cvt_bf16<<<gw, 256, 0, stream>>>(wv, wvb, n8);
        cvt_bf16<<<gw, 256, 0, stream>>>(wo, wob, n8);
    }
    int n8a = 16777216 / 8;
    dim3 ga((n8a + 255) / 256);
    dim3 gg((8192 / 256) * (2048 / 256));   // 256 blocks

    cvt_bf16<<<ga, 256, 0, stream>>>(q, comb, n8a);
    gemm256<0><<<gg, 512, 0, stream>>>(comb, wqb, qh, 8192, 2048, 2048, scale);
    cvt_bf16<<<ga, 256, 0, stream>>>(k, comb, n8a);
    gemm256<0><<<gg, 512, 0, stream>>>(comb, wkb, kh, 8192, 2048, 2048, 1.0f);
    cvt_bf16<<<ga, 256, 0, stream>>>(v, comb, n8a);
    gemm256<0><<<gg, 512, 0, stream>>>(comb, wvb, vh, 8192, 2048, 2048, 1.0f);

    attn_kernel<<<dim3(512), 512, 0, stream>>>(qh, kh, vh, mask, kpad, comb);

    gemm256<1><<<gg, 512, 0, stream>>>(comb, wob, out, 8192, 2048, 2048, 1.0f);
}

// Round 11
// 794.876 us; speedup vs baseline: 1.9826x; 1.9826x over previous
//
#include <hip/hip_runtime.h>
#include <hip/hip_bf16.h>
#include <stdint.h>

#define S_LEN 2048
#define D_MODEL 2048
#define NH 16
#define HD_DIM 128
#define BATCH 4

typedef unsigned short u16;
typedef unsigned int u32;
typedef short s16x8 __attribute__((ext_vector_type(8)));
typedef float f32x4 __attribute__((ext_vector_type(4)));

__device__ __forceinline__ u16 f2b(float f) {
    union { float f; u32 u; } v; v.f = f;
    u32 r = v.u + 0x7FFFu + ((v.u >> 16) & 1u);
    return (u16)(r >> 16);
}

__device__ __forceinline__ u32 cvtpk(float lo, float hi) {
    u32 r;
    asm volatile("v_cvt_pk_bf16_f32 %0, %1, %2" : "=v"(r) : "v"(lo), "v"(hi));
    return r;
}

#define BAR()   asm volatile("s_barrier" ::: "memory")
#define LGKM0() asm volatile("s_waitcnt lgkmcnt(0)" ::: "memory")
#define VMW(n)  asm volatile("s_waitcnt vmcnt(" #n ")" ::: "memory")

// ---------------- fp32 -> bf16 conversion (weights + activations) ----------------
__global__ __launch_bounds__(256) void cvt_bf16(const float* __restrict__ in,
                                                u16* __restrict__ out, int n8) {
    int i = blockIdx.x * 256 + threadIdx.x;
    if (i >= n8) return;
    const float4* p = reinterpret_cast<const float4*>(in) + (size_t)i * 2;
    float4 a = p[0], b = p[1];
    s16x8 o;
    o[0] = (short)f2b(a.x); o[1] = (short)f2b(a.y);
    o[2] = (short)f2b(a.z); o[3] = (short)f2b(a.w);
    o[4] = (short)f2b(b.x); o[5] = (short)f2b(b.y);
    o[6] = (short)f2b(b.z); o[7] = (short)f2b(b.w);
    *(reinterpret_cast<s16x8*>(out) + i) = o;
}

// ---------------- 256x256 8-phase NT GEMM: C = alpha * A[M,K] @ B[N,K]^T ----------------
// OUT_MODE: 0 = bf16 row-major C[M,N]; 1 = f32 row-major.
template<int OUT_MODE>
__global__ __launch_bounds__(512, 1) void gemm256(const u16* __restrict__ Ab,
                                                  const u16* __restrict__ Bw,
                                                  void* __restrict__ Cv,
                                                  int M, int N, int K, float alpha) {
    __shared__ u16 lds[2][2][256 * 64];
    const int t = threadIdx.x, lane = t & 63, w = t >> 6;
    const int wm = w >> 2, wn = w & 3;
    const int lr = lane & 15, lk = lane >> 4;
    const int NT = K >> 6;

    // bijective XCD swizzle (gridDim.x % 8 == 0 for all launches here)
    const int ntile = N >> 8;
    int flat = blockIdx.x;
    int cpx = gridDim.x >> 3;
    int rmap = (flat & 7) * cpx + (flat >> 3);
    const int m0 = (rmap / ntile) * 256, n0 = (rmap % ntile) * 256;

    // staging constants: thread covers row q*64 + (t>>3), position chunk t&7
    const int srow = t >> 3;
    const int spos = t & 7;
    const int scon = spos ^ (srow & 7);   // content chunk (pre-swizzled source)

    auto stage = [&](const u16* gbase, int grow0, int ldsT, int buf, int q, int kt) {
        const u16* src = gbase + (size_t)(grow0 + q * 64 + srow) * K + kt * 64 + scon * 8;
        u16* dst = &lds[buf][ldsT][(q * 64 + srow) * 64 + spos * 8];
        __builtin_amdgcn_global_load_lds(
            (const __attribute__((address_space(1))) void*)src,
            (__attribute__((address_space(3))) void*)dst, 16, 0, 0);
    };

    f32x4 acc[8][4];
#pragma unroll
    for (int i = 0; i < 8; ++i)
#pragma unroll
        for (int j = 0; j < 4; ++j) acc[i][j] = {0.f, 0.f, 0.f, 0.f};

    s16x8 a[4][2], b[4][2];

    // prologue: tile 0, order BQ0-3, AQ0, AQ2, AQ1, AQ3 (A-upper last)
    stage(Bw, n0, 1, 0, 0, 0);
    stage(Bw, n0, 1, 0, 1, 0);
    stage(Bw, n0, 1, 0, 2, 0);
    stage(Bw, n0, 1, 0, 3, 0);
    stage(Ab, m0, 0, 0, 0, 0);
    stage(Ab, m0, 0, 0, 2, 0);
    stage(Ab, m0, 0, 0, 1, 0);
    stage(Ab, m0, 0, 0, 3, 0);
    VMW(2);
    BAR();

#define LDFRAG(base, row, kk) \
    (*(const s16x8*)((base) + (row) * 64 + ((((kk) * 4 + lk) ^ (lr & 7)) << 3)))

#define QUAD(mh, nh)                                                                   \
    __builtin_amdgcn_s_setprio(1);                                                     \
    _Pragma("unroll")                                                                  \
    for (int mf = 0; mf < 4; ++mf)                                                     \
        _Pragma("unroll")                                                              \
        for (int nf = 0; nf < 2; ++nf)                                                 \
            _Pragma("unroll")                                                          \
            for (int kk = 0; kk < 2; ++kk)                                             \
                acc[(mh) * 4 + mf][(nh) * 2 + nf] = __builtin_amdgcn_mfma_f32_16x16x32_bf16( \
                    a[mf][kk], b[(nh) * 2 + nf][kk], acc[(mh) * 4 + mf][(nh) * 2 + nf], 0, 0, 0); \
    __builtin_amdgcn_s_setprio(0);

    for (int kt = 0; kt < NT; ++kt) {
        const int buf = kt & 1;
        const u16* la = &lds[buf][0][0];
        const u16* lb = &lds[buf][1][0];
        const int nx = kt + 1;
        const bool st = nx < NT;

        // ---- phase 0: quadrant (0,0) ----
#pragma unroll
        for (int mf = 0; mf < 4; ++mf)
#pragma unroll
            for (int kk = 0; kk < 2; ++kk)
                a[mf][kk] = LDFRAG(la, wm * 128 + mf * 16 + lr, kk);
#pragma unroll
        for (int nf = 0; nf < 2; ++nf)
#pragma unroll
            for (int kk = 0; kk < 2; ++kk)
                b[nf][kk] = LDFRAG(lb, wn * 64 + nf * 16 + lr, kk);
        if (st) { stage(Bw, n0, 1, buf ^ 1, 0, nx); stage(Bw, n0, 1, buf ^ 1, 1, nx); }
        BAR();
        LGKM0();
        QUAD(0, 0);
        BAR();

        // ---- phase 1: quadrant (0,1) ----
#pragma unroll
        for (int nf = 2; nf < 4; ++nf)
#pragma unroll
            for (int kk = 0; kk < 2; ++kk)
                b[nf][kk] = LDFRAG(lb, wn * 64 + nf * 16 + lr, kk);
        if (st) { stage(Bw, n0, 1, buf ^ 1, 2, nx); stage(Bw, n0, 1, buf ^ 1, 3, nx); }
        BAR();
        LGKM0();
        QUAD(0, 1);
        if (kt == NT - 1) { VMW(0); } else { VMW(4); }   // current tile's A-upper landed
        BAR();

        // ---- phase 2: quadrant (1,0) ----
#pragma unroll
        for (int mf = 0; mf < 4; ++mf)
#pragma unroll
            for (int kk = 0; kk < 2; ++kk)
                a[mf][kk] = LDFRAG(la, wm * 128 + 64 + mf * 16 + lr, kk);
        if (st) { stage(Ab, m0, 0, buf ^ 1, 0, nx); stage(Ab, m0, 0, buf ^ 1, 2, nx); }
        BAR();
        LGKM0();
        QUAD(1, 0);
        BAR();

        // ---- phase 3: quadrant (1,1) ----
        if (st) { stage(Ab, m0, 0, buf ^ 1, 1, nx); stage(Ab, m0, 0, buf ^ 1, 3, nx); }
        BAR();
        QUAD(1, 1);
        VMW(2);   // next tile's first 6 quarters landed
        BAR();
    }

    // epilogue: C layout col = lr, row = lk*4 + reg
#pragma unroll
    for (int i = 0; i < 8; ++i)
#pragma unroll
        for (int j = 0; j < 4; ++j) {
            int r0 = m0 + wm * 128 + (i >> 2) * 64 + (i & 3) * 16 + lk * 4;
            int c0 = n0 + wn * 64 + j * 16 + lr;
            if constexpr (OUT_MODE == 1) {
                float* C = (float*)Cv;
#pragma unroll
                for (int r = 0; r < 4; ++r) C[(size_t)(r0 + r) * N + c0] = acc[i][j][r] * alpha;
            } else {
                u16* C = (u16*)Cv;
#pragma unroll
                for (int r = 0; r < 4; ++r) C[(size_t)(r0 + r) * N + c0] = f2b(acc[i][j][r] * alpha);
            }
        }
}

// ---------------- flash attention ----------------
// Round-9 proven protocol (V dbuf LDS shfl-transpose, K dbuf global_load_lds,
// ONE __syncthreads/tile, defer-max, mask/kpad reg-prefetch) with KVBLK 64 -> 32:
// LDS 64 KiB -> 32 KiB => 4 blocks/CU (grid 1024 = exactly 4/CU), VGPR shrinks
// (smaller sc/mreg/lo-hi arrays) => 4 waves/SIMD vs round-9's 2. Per-kv work
// identical; 64 iterations of a half-size tile. Round-10's spill trap avoided:
// bound (256,3) caps at ~170 VGPR (actual ~120), never force-capping to 64.
__global__ __launch_bounds__(256, 3) void attn_kernel(
    const u16* __restrict__ Qh, const u16* __restrict__ Kh, const u16* __restrict__ Vh,
    const float* __restrict__ mask, const float* __restrict__ kpad,
    u16* __restrict__ Comb) {
    __shared__ u16 Ks[2][32 * 128];
    __shared__ u16 Vt[2][128 * 32];

    const int t = threadIdx.x, lane = t & 63, w = t >> 6;
    const int lr = lane & 15, lk = lane >> 4;

    const int g = blockIdx.x;
    const int rm = (g & 7) * 128 + (g >> 3);     // 1024 % 8 == 0: bijective
    const int qb = rm & 15, h = (rm >> 4) & 15, b = rm >> 8;   // qb fast (L3-friendly)
    const int q0w = qb * 128 + w * 32;
    const size_t rowBase = (size_t)b * S_LEN;
    const u16* Kb = Kh + rowBase * D_MODEL + h * HD_DIM;
    const u16* Vb = Vh + rowBase * D_MODEL + h * HD_DIM;

    // Q fragments (B operand): q = q0w + qi*16 + lr, d = dc*32 + lk*8 + j. (scale pre-folded)
    s16x8 qf[2][4];
#pragma unroll
    for (int qi = 0; qi < 2; ++qi)
#pragma unroll
        for (int dc = 0; dc < 4; ++dc)
            qf[qi][dc] = *(const s16x8*)(Qh + (rowBase + q0w + qi * 16 + lr) * D_MODEL +
                                         h * HD_DIM + dc * 32 + lk * 8);

    f32x4 o[2][8];
#pragma unroll
    for (int qi = 0; qi < 2; ++qi)
#pragma unroll
        for (int dt = 0; dt < 8; ++dt) o[qi][dt] = {0.f, 0.f, 0.f, 0.f};
    float m_[2] = {-3e38f, -3e38f}, l_[2] = {0.f, 0.f};

    // K staging (32 rows, 2 passes of 16): LDS dest linear, content chunk = pos ^ (row&7)
    const int ksub = t >> 4;                          // 0..15
    const int kchunk = (t & 15) ^ (ksub & 7);         // pre-swizzled global chunk
    // V staging (32 rows, one pass): vrow = t>>3 in 0..31
    const int vrow = t >> 3;
    const int vc0 = (t & 7) * 16;
    const int vodd = vrow & 1;
    const int vp = t >> 4;                            // kv-pair 0..15

    s16x8 va0, va1;

    auto stageK = [&](int kv0, int nb) {
#pragma unroll
        for (int p = 0; p < 2; ++p) {
            const u16* src = Kb + (size_t)(kv0 + p * 16 + ksub) * D_MODEL + kchunk * 8;
            __builtin_amdgcn_global_load_lds(
                (const __attribute__((address_space(1))) void*)src,
                (__attribute__((address_space(3))) void*)(&Ks[nb][p * 2048 + t * 8]), 16, 0, 0);
        }
    };
    auto loadV = [&](int kv0) {
        const u16* p0 = Vb + (size_t)(kv0 + vrow) * D_MODEL + vc0;
        va0 = *(const s16x8*)p0;
        va1 = *(const s16x8*)(p0 + 8);
    };
    // Vt[d][kv], 32 kv/row; kv-chunk c (8 kv = 16B) stored at position c ^ S(d),
    // S(d) = (d&3)^((d>>2)&3) -> PV b128 reads are 2-way (free) bank aliased.
    auto writeV = [&](int nb) {
        union VU { s16x8 v[2]; u32 uw[8]; u16 us[16]; };
        VU A;
        A.v[0] = va0; A.v[1] = va1;
        u32 ra[4];
#pragma unroll
        for (int i = 0; i < 4; ++i)
            ra[i] = (u32)__shfl_xor((int)(vodd ? A.uw[i] : A.uw[i + 4]), 8, 64);
#pragma unroll
        for (int e = 0; e < 8; ++e) {
            int d = vc0 + vodd * 8 + e;
            int S = (d & 3) ^ ((d >> 2) & 3);
            u16 rau = (u16)((ra[e >> 1] >> ((e & 1) * 16)) & 0xffff);
            u16 lo1, hi1;
            if (vodd) { lo1 = rau; hi1 = A.us[8 + e]; }
            else      { lo1 = A.us[e]; hi1 = rau; }
            int cp = (vp >> 2) ^ S;
            *(u32*)(&Vt[nb][d * 32 + cp * 8 + (vp & 3) * 2]) = (u32)lo1 | ((u32)hi1 << 16);
        }
    };

    // mask/kpad register prefetch (one tile ahead)
    f32x4 mreg[2][2], kreg[2];
    auto loadMask = [&](int kv0) {
#pragma unroll
        for (int qi = 0; qi < 2; ++qi) {
            const float* mrow = mask + (size_t)(q0w + qi * 16 + lr) * S_LEN + kv0;
#pragma unroll
            for (int kt = 0; kt < 2; ++kt)
                mreg[qi][kt] = *(const f32x4*)(mrow + kt * 16 + lk * 4);
        }
#pragma unroll
        for (int kt = 0; kt < 2; ++kt)
            kreg[kt] = *(const f32x4*)(kpad + b * S_LEN + kv0 + kt * 16 + lk * 4);
    };

    // prologue: stage tile 0
    stageK(0, 0);
    loadV(0);
    writeV(0);
    loadMask(0);
    __syncthreads();

    const int srcA = ((lk & 1) * 32) + lr;   // lane holding lk' = (lk&1)*2
    const int srcB = srcA + 16;
    const int vswz = (lr & 3) ^ ((lr >> 2) & 3);

    for (int i = 0; i < 64; ++i) {
        const int cur = i & 1;
        const u16* ks = &Ks[cur][0];
        const u16* vt = &Vt[cur][0];
        const int kv0 = i * 32;

        if (i < 63) { stageK(kv0 + 32, cur ^ 1); loadV(kv0 + 32); }

        // QK^T (swapped): sc[qi][kt]: lane holds S[kv=kt*16+lk*4+r][q=qi*16+lr]
        f32x4 sc[2][2];
#pragma unroll
        for (int qi = 0; qi < 2; ++qi)
#pragma unroll
            for (int kt = 0; kt < 2; ++kt) sc[qi][kt] = {0.f, 0.f, 0.f, 0.f};
        __builtin_amdgcn_s_setprio(1);
#pragma unroll
        for (int kt = 0; kt < 2; ++kt) {
            s16x8 kf[4];
#pragma unroll
            for (int dc = 0; dc < 4; ++dc)
                kf[dc] = *(const s16x8*)(&ks[(kt * 16 + lr) * 128 +
                                             (((dc * 4 + lk) ^ (lr & 7)) << 3)]);
#pragma unroll
            for (int dc = 0; dc < 4; ++dc) {
                sc[0][kt] = __builtin_amdgcn_mfma_f32_16x16x32_bf16(kf[dc], qf[0][dc], sc[0][kt], 0, 0, 0);
                sc[1][kt] = __builtin_amdgcn_mfma_f32_16x16x32_bf16(kf[dc], qf[1][dc], sc[1][kt], 0, 0, 0);
            }
        }
        __builtin_amdgcn_s_setprio(0);

        // masks (prefetched regs) + online softmax (per-lane row-local: q = lr)
        u32 lo[2][2], hi[2][2];
#pragma unroll
        for (int qi = 0; qi < 2; ++qi) {
            float s[8];
            float mx = -3e38f;
#pragma unroll
            for (int kt = 0; kt < 2; ++kt)
#pragma unroll
                for (int r = 0; r < 4; ++r) {
                    float v = sc[qi][kt][r] + mreg[qi][kt][r] + kreg[kt][r];
                    s[kt * 4 + r] = v;
                    mx = fmaxf(mx, v);
                }
            mx = fmaxf(mx, __shfl_xor(mx, 16, 64));
            mx = fmaxf(mx, __shfl_xor(mx, 32, 64));
            // defer-max (T13, THR=8): rescale only when the running max grows
            if (__any(mx > m_[qi] + 8.0f)) {
                float mn = fmaxf(m_[qi], mx);
                float fs = __expf(m_[qi] - mn);
                m_[qi] = mn;
                l_[qi] *= fs;
#pragma unroll
                for (int r = 0; r < 4; ++r) {
                    float fsb = __shfl(fs, (lane & 48) | (lk * 4 + r), 64);
#pragma unroll
                    for (int dt = 0; dt < 8; ++dt) o[qi][dt][r] *= fsb;
                }
            }
            float ls = 0.f;
#pragma unroll
            for (int e = 0; e < 8; ++e) { s[e] = __expf(s[e] - m_[qi]); ls += s[e]; }
            ls += __shfl_xor(ls, 16, 64);
            ls += __shfl_xor(ls, 32, 64);
            l_[qi] += ls;
#pragma unroll
            for (int kt = 0; kt < 2; ++kt) {
                lo[qi][kt] = cvtpk(s[kt * 4 + 0], s[kt * 4 + 1]);
                hi[qi][kt] = cvtpk(s[kt * 4 + 2], s[kt * 4 + 3]);
            }
        }

        // prefetch next tile's mask/kpad (regs free after s[] computed above)
        if (i < 63) loadMask(kv0 + 32);

        // redistribute P (C-layout) -> A-frag in-register (single 32-kv group)
        s16x8 pf[2];
        const bool sel = (lk >> 1) & 1;
#pragma unroll
        for (int qi = 0; qi < 2; ++qi) {
            u32 w0a = (u32)__shfl((int)lo[qi][0], srcA, 64);
            u32 w0b = (u32)__shfl((int)lo[qi][1], srcA, 64);
            u32 w1a = (u32)__shfl((int)hi[qi][0], srcA, 64);
            u32 w1b = (u32)__shfl((int)hi[qi][1], srcA, 64);
            u32 w2a = (u32)__shfl((int)lo[qi][0], srcB, 64);
            u32 w2b = (u32)__shfl((int)lo[qi][1], srcB, 64);
            u32 w3a = (u32)__shfl((int)hi[qi][0], srcB, 64);
            u32 w3b = (u32)__shfl((int)hi[qi][1], srcB, 64);
            union { s16x8 v; u32 u[4]; } P;
            P.u[0] = sel ? w0b : w0a;
            P.u[1] = sel ? w1b : w1a;
            P.u[2] = sel ? w2b : w2a;
            P.u[3] = sel ? w3b : w3a;
            pf[qi] = P.v;
        }

        // PV: o[qi][dt] += P[16x32] @ V[32x16]
        __builtin_amdgcn_s_setprio(1);
#pragma unroll
        for (int dt = 0; dt < 8; ++dt) {
            s16x8 vf = *(const s16x8*)(&vt[(dt * 16 + lr) * 32 + ((lk ^ vswz) << 3)]);
            o[0][dt] = __builtin_amdgcn_mfma_f32_16x16x32_bf16(pf[0], vf, o[0][dt], 0, 0, 0);
            o[1][dt] = __builtin_amdgcn_mfma_f32_16x16x32_bf16(pf[1], vf, o[1][dt], 0, 0, 0);
        }
        __builtin_amdgcn_s_setprio(0);

        if (i < 63) writeV(cur ^ 1);
        __syncthreads();
    }

    // epilogue: O = o / l; o C-layout: q = qi*16 + lk*4 + r, d = dt*16 + lr
#pragma unroll
    for (int qi = 0; qi < 2; ++qi)
#pragma unroll
        for (int r = 0; r < 4; ++r) {
            float lb = __shfl(l_[qi], (lane & 48) | (lk * 4 + r), 64);
            float inv = 1.0f / lb;
            size_t row = rowBase + q0w + qi * 16 + lk * 4 + r;
            u16* dst = Comb + row * D_MODEL + h * HD_DIM + lr;
#pragma unroll
            for (int dt = 0; dt < 8; ++dt) dst[dt * 16] = f2b(o[qi][dt][r] * inv);
        }
}

extern "C" void kernel_launch(void* const* d_in, const int* in_sizes, int n_in,
                              void* d_out, int out_size, void* d_ws, size_t ws_size,
                              hipStream_t stream) {
    const float* q    = (const float*)d_in[0];
    const float* k    = (const float*)d_in[1];
    const float* v    = (const float*)d_in[2];
    const float* mask = (const float*)d_in[3];
    const float* kpad = (const float*)d_in[4];
    const float* wq   = (const float*)d_in[5];
    const float* wk   = (const float*)d_in[6];
    const float* wv   = (const float*)d_in[7];
    const float* wo   = (const float*)d_in[8];
    float* out = (float*)d_out;

    u16* wqb  = (u16*)d_ws;                 // 2048*2048 bf16 each
    u16* wkb  = wqb + 4194304;
    u16* wvb  = wkb + 4194304;
    u16* wob  = wvb + 4194304;
    u16* qh   = wob + 4194304;              // 8192*2048 bf16 each
    u16* kh   = qh + 16777216;
    u16* vh   = kh + 16777216;
    u16* comb = vh + 16777216;              // doubles as activation bf16 staging
    // total: 160 MB

    const float scale = 0.08838834764831845f;  // 1/sqrt(128), folded into Q projection

    {
        int n8 = 4194304 / 8;
        dim3 gw((n8 + 255) / 256);
        cvt_bf16<<<gw, 256, 0, stream>>>(wq, wqb, n8);
        cvt_bf16<<<gw, 256, 0, stream>>>(wk, wkb, n8);
        cvt_bf16<<<gw, 256, 0, stream>>>(wv, wvb, n8);
        cvt_bf16<<<gw, 256, 0, stream>>>(wo, wob, n8);
    }
    int n8a = 16777216 / 8;
    dim3 ga((n8a + 255) / 256);
    dim3 gg((8192 / 256) * (2048 / 256));   // 256 blocks

    cvt_bf16<<<ga, 256, 0, stream>>>(q, comb, n8a);
    gemm256<0><<<gg, 512, 0, stream>>>(comb, wqb, qh, 8192, 2048, 2048, scale);
    cvt_bf16<<<ga, 256, 0, stream>>>(k, comb, n8a);
    gemm256<0><<<gg, 512, 0, stream>>>(comb, wkb, kh, 8192, 2048, 2048, 1.0f);
    cvt_bf16<<<ga, 256, 0, stream>>>(v, comb, n8a);
    gemm256<0><<<gg, 512, 0, stream>>>(comb, wvb, vh, 8192, 2048, 2048, 1.0f);

    attn_kernel<<<dim3(1024), 256, 0, stream>>>(qh, kh, vh, mask, kpad, comb);

    gemm256<1><<<gg, 512, 0, stream>>>(comb, wob, out, 8192, 2048, 2048, 1.0f);
}

// Round 12
// 593.843 us; speedup vs baseline: 2.6538x; 1.3385x over previous
//
#include <hip/hip_runtime.h>
#include <hip/hip_bf16.h>
#include <stdint.h>

#define S_LEN 2048
#define D_MODEL 2048
#define NH 16
#define HD_DIM 128
#define BATCH 4

typedef unsigned short u16;
typedef unsigned int u32;
typedef short s16x8 __attribute__((ext_vector_type(8)));
typedef float f32x4 __attribute__((ext_vector_type(4)));

__device__ __forceinline__ u16 f2b(float f) {
    union { float f; u32 u; } v; v.f = f;
    u32 r = v.u + 0x7FFFu + ((v.u >> 16) & 1u);
    return (u16)(r >> 16);
}

__device__ __forceinline__ u32 cvtpk(float lo, float hi) {
    u32 r;
    asm volatile("v_cvt_pk_bf16_f32 %0, %1, %2" : "=v"(r) : "v"(lo), "v"(hi));
    return r;
}

#define BAR()   asm volatile("s_barrier" ::: "memory")
#define LGKM0() asm volatile("s_waitcnt lgkmcnt(0)" ::: "memory")
#define VMW(n)  asm volatile("s_waitcnt vmcnt(" #n ")" ::: "memory")

// ---------------- fp32 -> bf16 conversion (weights + activations) ----------------
__global__ __launch_bounds__(256) void cvt_bf16(const float* __restrict__ in,
                                                u16* __restrict__ out, int n8) {
    int i = blockIdx.x * 256 + threadIdx.x;
    if (i >= n8) return;
    const float4* p = reinterpret_cast<const float4*>(in) + (size_t)i * 2;
    float4 a = p[0], b = p[1];
    s16x8 o;
    o[0] = (short)f2b(a.x); o[1] = (short)f2b(a.y);
    o[2] = (short)f2b(a.z); o[3] = (short)f2b(a.w);
    o[4] = (short)f2b(b.x); o[5] = (short)f2b(b.y);
    o[6] = (short)f2b(b.z); o[7] = (short)f2b(b.w);
    *(reinterpret_cast<s16x8*>(out) + i) = o;
}

// ---------------- 256x256 8-phase NT GEMM: C = alpha * A[M,K] @ B[N,K]^T ----------------
// OUT_MODE: 0 = bf16 row-major C[M,N]; 1 = f32 row-major.
template<int OUT_MODE>
__global__ __launch_bounds__(512, 1) void gemm256(const u16* __restrict__ Ab,
                                                  const u16* __restrict__ Bw,
                                                  void* __restrict__ Cv,
                                                  int M, int N, int K, float alpha) {
    __shared__ u16 lds[2][2][256 * 64];
    const int t = threadIdx.x, lane = t & 63, w = t >> 6;
    const int wm = w >> 2, wn = w & 3;
    const int lr = lane & 15, lk = lane >> 4;
    const int NT = K >> 6;

    // bijective XCD swizzle (gridDim.x % 8 == 0 for all launches here)
    const int ntile = N >> 8;
    int flat = blockIdx.x;
    int cpx = gridDim.x >> 3;
    int rmap = (flat & 7) * cpx + (flat >> 3);
    const int m0 = (rmap / ntile) * 256, n0 = (rmap % ntile) * 256;

    // staging constants: thread covers row q*64 + (t>>3), position chunk t&7
    const int srow = t >> 3;
    const int spos = t & 7;
    const int scon = spos ^ (srow & 7);   // content chunk (pre-swizzled source)

    auto stage = [&](const u16* gbase, int grow0, int ldsT, int buf, int q, int kt) {
        const u16* src = gbase + (size_t)(grow0 + q * 64 + srow) * K + kt * 64 + scon * 8;
        u16* dst = &lds[buf][ldsT][(q * 64 + srow) * 64 + spos * 8];
        __builtin_amdgcn_global_load_lds(
            (const __attribute__((address_space(1))) void*)src,
            (__attribute__((address_space(3))) void*)dst, 16, 0, 0);
    };

    f32x4 acc[8][4];
#pragma unroll
    for (int i = 0; i < 8; ++i)
#pragma unroll
        for (int j = 0; j < 4; ++j) acc[i][j] = {0.f, 0.f, 0.f, 0.f};

    s16x8 a[4][2], b[4][2];

    // prologue: tile 0, order BQ0-3, AQ0, AQ2, AQ1, AQ3 (A-upper last)
    stage(Bw, n0, 1, 0, 0, 0);
    stage(Bw, n0, 1, 0, 1, 0);
    stage(Bw, n0, 1, 0, 2, 0);
    stage(Bw, n0, 1, 0, 3, 0);
    stage(Ab, m0, 0, 0, 0, 0);
    stage(Ab, m0, 0, 0, 2, 0);
    stage(Ab, m0, 0, 0, 1, 0);
    stage(Ab, m0, 0, 0, 3, 0);
    VMW(2);
    BAR();

#define LDFRAG(base, row, kk) \
    (*(const s16x8*)((base) + (row) * 64 + ((((kk) * 4 + lk) ^ (lr & 7)) << 3)))

#define QUAD(mh, nh)                                                                   \
    __builtin_amdgcn_s_setprio(1);                                                     \
    _Pragma("unroll")                                                                  \
    for (int mf = 0; mf < 4; ++mf)                                                     \
        _Pragma("unroll")                                                              \
        for (int nf = 0; nf < 2; ++nf)                                                 \
            _Pragma("unroll")                                                          \
            for (int kk = 0; kk < 2; ++kk)                                             \
                acc[(mh) * 4 + mf][(nh) * 2 + nf] = __builtin_amdgcn_mfma_f32_16x16x32_bf16( \
                    a[mf][kk], b[(nh) * 2 + nf][kk], acc[(mh) * 4 + mf][(nh) * 2 + nf], 0, 0, 0); \
    __builtin_amdgcn_s_setprio(0);

    for (int kt = 0; kt < NT; ++kt) {
        const int buf = kt & 1;
        const u16* la = &lds[buf][0][0];
        const u16* lb = &lds[buf][1][0];
        const int nx = kt + 1;
        const bool st = nx < NT;

        // ---- phase 0: quadrant (0,0) ----
#pragma unroll
        for (int mf = 0; mf < 4; ++mf)
#pragma unroll
            for (int kk = 0; kk < 2; ++kk)
                a[mf][kk] = LDFRAG(la, wm * 128 + mf * 16 + lr, kk);
#pragma unroll
        for (int nf = 0; nf < 2; ++nf)
#pragma unroll
            for (int kk = 0; kk < 2; ++kk)
                b[nf][kk] = LDFRAG(lb, wn * 64 + nf * 16 + lr, kk);
        if (st) { stage(Bw, n0, 1, buf ^ 1, 0, nx); stage(Bw, n0, 1, buf ^ 1, 1, nx); }
        BAR();
        LGKM0();
        QUAD(0, 0);
        BAR();

        // ---- phase 1: quadrant (0,1) ----
#pragma unroll
        for (int nf = 2; nf < 4; ++nf)
#pragma unroll
            for (int kk = 0; kk < 2; ++kk)
                b[nf][kk] = LDFRAG(lb, wn * 64 + nf * 16 + lr, kk);
        if (st) { stage(Bw, n0, 1, buf ^ 1, 2, nx); stage(Bw, n0, 1, buf ^ 1, 3, nx); }
        BAR();
        LGKM0();
        QUAD(0, 1);
        if (kt == NT - 1) { VMW(0); } else { VMW(4); }   // current tile's A-upper landed
        BAR();

        // ---- phase 2: quadrant (1,0) ----
#pragma unroll
        for (int mf = 0; mf < 4; ++mf)
#pragma unroll
            for (int kk = 0; kk < 2; ++kk)
                a[mf][kk] = LDFRAG(la, wm * 128 + 64 + mf * 16 + lr, kk);
        if (st) { stage(Ab, m0, 0, buf ^ 1, 0, nx); stage(Ab, m0, 0, buf ^ 1, 2, nx); }
        BAR();
        LGKM0();
        QUAD(1, 0);
        BAR();

        // ---- phase 3: quadrant (1,1) ----
        if (st) { stage(Ab, m0, 0, buf ^ 1, 1, nx); stage(Ab, m0, 0, buf ^ 1, 3, nx); }
        BAR();
        QUAD(1, 1);
        VMW(2);   // next tile's first 6 quarters landed
        BAR();
    }

    // epilogue: C layout col = lr, row = lk*4 + reg
#pragma unroll
    for (int i = 0; i < 8; ++i)
#pragma unroll
        for (int j = 0; j < 4; ++j) {
            int r0 = m0 + wm * 128 + (i >> 2) * 64 + (i & 3) * 16 + lk * 4;
            int c0 = n0 + wn * 64 + j * 16 + lr;
            if constexpr (OUT_MODE == 1) {
                float* C = (float*)Cv;
#pragma unroll
                for (int r = 0; r < 4; ++r) C[(size_t)(r0 + r) * N + c0] = acc[i][j][r] * alpha;
            } else {
                u16* C = (u16*)Cv;
#pragma unroll
                for (int r = 0; r < 4; ++r) C[(size_t)(r0 + r) * N + c0] = f2b(acc[i][j][r] * alpha);
            }
        }
}

// ---------------- flash attention ----------------
// Round-10 kernel (correctness-proven: passed with absmax 2.9e-3) with the spill
// diagnosed and fixed: __launch_bounds__(512,4) forced a 64-VGPR cap (2nd arg is
// min BLOCKS/CU: 4 blocks x 8 waves = 32 waves/CU -> 64 VGPR -> scratch spill,
// FETCH 2.75 GB). Now (512,2): 2 blocks/CU x 8 waves = 16 waves/CU = 4 waves/SIMD,
// VGPR cap 128 (= round-9's measured natural allocation; this variant holds less).
// Protocol unchanged: V dbuf LDS shfl-transpose, K dbuf global_load_lds, ONE
// __syncthreads/tile, defer-max, mask/kpad reg-prefetch. K/V staged once per 256
// q-rows (traffic halves vs round-9). Grid 512 = exactly 2 blocks/CU.
__global__ __launch_bounds__(512, 2) void attn_kernel(
    const u16* __restrict__ Qh, const u16* __restrict__ Kh, const u16* __restrict__ Vh,
    const float* __restrict__ mask, const float* __restrict__ kpad,
    u16* __restrict__ Comb) {
    __shared__ u16 Ks[2][64 * 128];
    __shared__ u16 Vt[2][128 * 64];

    const int t = threadIdx.x, lane = t & 63, w = t >> 6;   // w: 0..7
    const int lr = lane & 15, lk = lane >> 4;

    const int g = blockIdx.x;
    const int rm = (g & 7) * 64 + (g >> 3);      // 512 % 8 == 0: bijective
    const int qb = rm & 7, h = (rm >> 3) & 15, b = rm >> 7;  // qb fast (L3-friendly)
    const int q0w = qb * 256 + w * 32;
    const size_t rowBase = (size_t)b * S_LEN;
    const u16* Kb = Kh + rowBase * D_MODEL + h * HD_DIM;
    const u16* Vb = Vh + rowBase * D_MODEL + h * HD_DIM;

    // Q fragments (B operand): q = q0w + qi*16 + lr, d = dc*32 + lk*8 + j. (scale pre-folded)
    s16x8 qf[2][4];
#pragma unroll
    for (int qi = 0; qi < 2; ++qi)
#pragma unroll
        for (int dc = 0; dc < 4; ++dc)
            qf[qi][dc] = *(const s16x8*)(Qh + (rowBase + q0w + qi * 16 + lr) * D_MODEL +
                                         h * HD_DIM + dc * 32 + lk * 8);

    f32x4 o[2][8];
#pragma unroll
    for (int qi = 0; qi < 2; ++qi)
#pragma unroll
        for (int dt = 0; dt < 8; ++dt) o[qi][dt] = {0.f, 0.f, 0.f, 0.f};
    float m_[2] = {-3e38f, -3e38f}, l_[2] = {0.f, 0.f};

    // K staging (512 threads, 2 passes of 32 rows):
    // LDS row R = p*32 + (t>>4), position chunk t&15, content chunk = (t&15) ^ (R&7)
    const int ksub = t >> 4;                          // 0..31
    const int kchunk = (t & 15) ^ (ksub & 7);         // pre-swizzled global chunk
    // V staging (512 threads, one pass: row = t>>3 covers all 64 kv rows)
    const int vrow = t >> 3;                          // 0..63
    const int vc0 = (t & 7) * 16;
    const int vodd = vrow & 1;
    const int vp = t >> 4;                            // kv-pair 0..31

    s16x8 va0, va1;

    auto stageK = [&](int kv0, int nb) {
#pragma unroll
        for (int p = 0; p < 2; ++p) {
            const u16* src = Kb + (size_t)(kv0 + p * 32 + ksub) * D_MODEL + kchunk * 8;
            __builtin_amdgcn_global_load_lds(
                (const __attribute__((address_space(1))) void*)src,
                (__attribute__((address_space(3))) void*)(&Ks[nb][p * 4096 + t * 8]), 16, 0, 0);
        }
    };
    auto loadV = [&](int kv0) {
        const u16* p0 = Vb + (size_t)(kv0 + vrow) * D_MODEL + vc0;
        va0 = *(const s16x8*)p0;
        va1 = *(const s16x8*)(p0 + 8);
    };
    auto writeV = [&](int nb) {
        union VU { s16x8 v[2]; u32 uw[8]; u16 us[16]; };
        VU A;
        A.v[0] = va0; A.v[1] = va1;
        u32 ra[4];
#pragma unroll
        for (int i = 0; i < 4; ++i)
            ra[i] = (u32)__shfl_xor((int)(vodd ? A.uw[i] : A.uw[i + 4]), 8, 64);
#pragma unroll
        for (int e = 0; e < 8; ++e) {
            int d = vc0 + vodd * 8 + e;
            int swz = ((d >> 4) ^ (d & 7)) & 7;
            u16 rau = (u16)((ra[e >> 1] >> ((e & 1) * 16)) & 0xffff);
            u16 lo1, hi1;
            if (vodd) { lo1 = rau; hi1 = A.us[8 + e]; }
            else      { lo1 = A.us[e]; hi1 = rau; }
            int c1 = (vp >> 2) ^ swz;
            *(u32*)(&Vt[nb][d * 64 + c1 * 8 + (vp & 3) * 2]) = (u32)lo1 | ((u32)hi1 << 16);
        }
    };

    // mask/kpad register prefetch (one tile ahead)
    f32x4 mreg[2][4], kreg[4];
    auto loadMask = [&](int kv0) {
#pragma unroll
        for (int qi = 0; qi < 2; ++qi) {
            const float* mrow = mask + (size_t)(q0w + qi * 16 + lr) * S_LEN + kv0;
#pragma unroll
            for (int kt = 0; kt < 4; ++kt)
                mreg[qi][kt] = *(const f32x4*)(mrow + kt * 16 + lk * 4);
        }
#pragma unroll
        for (int kt = 0; kt < 4; ++kt)
            kreg[kt] = *(const f32x4*)(kpad + b * S_LEN + kv0 + kt * 16 + lk * 4);
    };

    // prologue: stage tile 0
    stageK(0, 0);
    loadV(0);
    writeV(0);
    loadMask(0);
    __syncthreads();

    const int srcA = ((lk & 1) * 32) + lr;   // lane holding lk' = (lk&1)*2
    const int srcB = srcA + 16;

    for (int i = 0; i < 32; ++i) {
        const int cur = i & 1;
        const u16* ks = &Ks[cur][0];
        const u16* vt = &Vt[cur][0];
        const int kv0 = i * 64;

        if (i < 31) { stageK(kv0 + 64, cur ^ 1); loadV(kv0 + 64); }

        // QK^T (swapped): sc[qi][kt]: lane holds S[kv=kt*16+lk*4+r][q=qi*16+lr]
        f32x4 sc[2][4];
#pragma unroll
        for (int qi = 0; qi < 2; ++qi)
#pragma unroll
            for (int kt = 0; kt < 4; ++kt) sc[qi][kt] = {0.f, 0.f, 0.f, 0.f};
        __builtin_amdgcn_s_setprio(1);
#pragma unroll
        for (int kt = 0; kt < 4; ++kt) {
            s16x8 kf[4];
#pragma unroll
            for (int dc = 0; dc < 4; ++dc)
                kf[dc] = *(const s16x8*)(&ks[(kt * 16 + lr) * 128 +
                                             (((dc * 4 + lk) ^ (lr & 7)) << 3)]);
#pragma unroll
            for (int dc = 0; dc < 4; ++dc) {
                sc[0][kt] = __builtin_amdgcn_mfma_f32_16x16x32_bf16(kf[dc], qf[0][dc], sc[0][kt], 0, 0, 0);
                sc[1][kt] = __builtin_amdgcn_mfma_f32_16x16x32_bf16(kf[dc], qf[1][dc], sc[1][kt], 0, 0, 0);
            }
        }
        __builtin_amdgcn_s_setprio(0);

        // masks (prefetched regs) + online softmax (per-lane row-local: q = lr)
        u32 lo[2][4], hi[2][4];
#pragma unroll
        for (int qi = 0; qi < 2; ++qi) {
            float s[16];
            float mx = -3e38f;
#pragma unroll
            for (int kt = 0; kt < 4; ++kt)
#pragma unroll
                for (int r = 0; r < 4; ++r) {
                    float v = sc[qi][kt][r] + mreg[qi][kt][r] + kreg[kt][r];
                    s[kt * 4 + r] = v;
                    mx = fmaxf(mx, v);
                }
            mx = fmaxf(mx, __shfl_xor(mx, 16, 64));
            mx = fmaxf(mx, __shfl_xor(mx, 32, 64));
            // defer-max (T13, THR=8): rescale only when the running max grows
            if (__any(mx > m_[qi] + 8.0f)) {
                float mn = fmaxf(m_[qi], mx);
                float fs = __expf(m_[qi] - mn);
                m_[qi] = mn;
                l_[qi] *= fs;
#pragma unroll
                for (int r = 0; r < 4; ++r) {
                    float fsb = __shfl(fs, (lane & 48) | (lk * 4 + r), 64);
#pragma unroll
                    for (int dt = 0; dt < 8; ++dt) o[qi][dt][r] *= fsb;
                }
            }
            float ls = 0.f;
#pragma unroll
            for (int e = 0; e < 16; ++e) { s[e] = __expf(s[e] - m_[qi]); ls += s[e]; }
            ls += __shfl_xor(ls, 16, 64);
            ls += __shfl_xor(ls, 32, 64);
            l_[qi] += ls;
#pragma unroll
            for (int kt = 0; kt < 4; ++kt) {
                lo[qi][kt] = cvtpk(s[kt * 4 + 0], s[kt * 4 + 1]);
                hi[qi][kt] = cvtpk(s[kt * 4 + 2], s[kt * 4 + 3]);
            }
        }

        // prefetch next tile's mask/kpad (regs free after s[] computed above)
        if (i < 31) loadMask(kv0 + 64);

        // redistribute P (C-layout) -> A-frag in-register
        s16x8 pf[2][2];
        const bool sel = (lk >> 1) & 1;
#pragma unroll
        for (int qi = 0; qi < 2; ++qi)
#pragma unroll
            for (int hh = 0; hh < 2; ++hh) {
                u32 w0a = (u32)__shfl((int)lo[qi][2 * hh], srcA, 64);
                u32 w0b = (u32)__shfl((int)lo[qi][2 * hh + 1], srcA, 64);
                u32 w1a = (u32)__shfl((int)hi[qi][2 * hh], srcA, 64);
                u32 w1b = (u32)__shfl((int)hi[qi][2 * hh + 1], srcA, 64);
                u32 w2a = (u32)__shfl((int)lo[qi][2 * hh], srcB, 64);
                u32 w2b = (u32)__shfl((int)lo[qi][2 * hh + 1], srcB, 64);
                u32 w3a = (u32)__shfl((int)hi[qi][2 * hh], srcB, 64);
                u32 w3b = (u32)__shfl((int)hi[qi][2 * hh + 1], srcB, 64);
                union { s16x8 v; u32 u[4]; } P;
                P.u[0] = sel ? w0b : w0a;
                P.u[1] = sel ? w1b : w1a;
                P.u[2] = sel ? w2b : w2a;
                P.u[3] = sel ? w3b : w3a;
                pf[qi][hh] = P.v;
            }

        // PV: o[qi][dt] += P[16x64] @ V[64x16]
        __builtin_amdgcn_s_setprio(1);
#pragma unroll
        for (int dt = 0; dt < 8; ++dt) {
            int swz = dt ^ (lr & 7);
            s16x8 vf0 = *(const s16x8*)(&vt[(dt * 16 + lr) * 64 + ((lk ^ swz) << 3)]);
            s16x8 vf1 = *(const s16x8*)(&vt[(dt * 16 + lr) * 64 + (((4 + lk) ^ swz) << 3)]);
            o[0][dt] = __builtin_amdgcn_mfma_f32_16x16x32_bf16(pf[0][0], vf0, o[0][dt], 0, 0, 0);
            o[1][dt] = __builtin_amdgcn_mfma_f32_16x16x32_bf16(pf[1][0], vf0, o[1][dt], 0, 0, 0);
            o[0][dt] = __builtin_amdgcn_mfma_f32_16x16x32_bf16(pf[0][1], vf1, o[0][dt], 0, 0, 0);
            o[1][dt] = __builtin_amdgcn_mfma_f32_16x16x32_bf16(pf[1][1], vf1, o[1][dt], 0, 0, 0);
        }
        __builtin_amdgcn_s_setprio(0);

        if (i < 31) writeV(cur ^ 1);
        __syncthreads();
    }

    // epilogue: O = o / l; o C-layout: q = qi*16 + lk*4 + r, d = dt*16 + lr
#pragma unroll
    for (int qi = 0; qi < 2; ++qi)
#pragma unroll
        for (int r = 0; r < 4; ++r) {
            float lb = __shfl(l_[qi], (lane & 48) | (lk * 4 + r), 64);
            float inv = 1.0f / lb;
            size_t row = rowBase + q0w + qi * 16 + lk * 4 + r;
            u16* dst = Comb + row * D_MODEL + h * HD_DIM + lr;
#pragma unroll
            for (int dt = 0; dt < 8; ++dt) dst[dt * 16] = f2b(o[qi][dt][r] * inv);
        }
}

extern "C" void kernel_launch(void* const* d_in, const int* in_sizes, int n_in,
                              void* d_out, int out_size, void* d_ws, size_t ws_size,
                              hipStream_t stream) {
    const float* q    = (const float*)d_in[0];
    const float* k    = (const float*)d_in[1];
    const float* v    = (const float*)d_in[2];
    const float* mask = (const float*)d_in[3];
    const float* kpad = (const float*)d_in[4];
    const float* wq   = (const float*)d_in[5];
    const float* wk   = (const float*)d_in[6];
    const float* wv   = (const float*)d_in[7];
    const float* wo   = (const float*)d_in[8];
    float* out = (float*)d_out;

    u16* wqb  = (u16*)d_ws;                 // 2048*2048 bf16 each
    u16* wkb  = wqb + 4194304;
    u16* wvb  = wkb + 4194304;
    u16* wob  = wvb + 4194304;
    u16* qh   = wob + 4194304;              // 8192*2048 bf16 each
    u16* kh   = qh + 16777216;
    u16* vh   = kh + 16777216;
    u16* comb = vh + 16777216;              // doubles as activation bf16 staging
    // total: 160 MB

    const float scale = 0.08838834764831845f;  // 1/sqrt(128), folded into Q projection

    {
        int n8 = 4194304 / 8;
        dim3 gw((n8 + 255) / 256);
        cvt_bf16<<<gw, 256, 0, stream>>>(wq, wqb, n8);
        cvt_bf16<<<gw, 256, 0, stream>>>(wk, wkb, n8);
        cvt_bf16<<<gw, 256, 0, stream>>>(wv, wvb, n8);
        cvt_bf16<<<gw, 256, 0, stream>>>(wo, wob, n8);
    }
    int n8a = 16777216 / 8;
    dim3 ga((n8a + 255) / 256);
    dim3 gg((8192 / 256) * (2048 / 256));   // 256 blocks

    cvt_bf16<<<ga, 256, 0, stream>>>(q, comb, n8a);
    gemm256<0><<<gg, 512, 0, stream>>>(comb, wqb, qh, 8192, 2048, 2048, scale);
    cvt_bf16<<<ga, 256, 0, stream>>>(k, comb, n8a);
    gemm256<0><<<gg, 512, 0, stream>>>(comb, wkb, kh, 8192, 2048, 2048, 1.0f);
    cvt_bf16<<<ga, 256, 0, stream>>>(v, comb, n8a);
    gemm256<0><<<gg, 512, 0, stream>>>(comb, wvb, vh, 8192, 2048, 2048, 1.0f);

    attn_kernel<<<dim3(512), 512, 0, stream>>>(qh, kh, vh, mask, kpad, comb);

    gemm256<1><<<gg, 512, 0, stream>>>(comb, wob, out, 8192, 2048, 2048, 1.0f);
}

// Round 13
// 584.791 us; speedup vs baseline: 2.6949x; 1.0155x over previous
//
#include <hip/hip_runtime.h>
#include <hip/hip_bf16.h>
#include <stdint.h>

#define S_LEN 2048
#define D_MODEL 2048
#define NH 16
#define HD_DIM 128
#define BATCH 4

typedef unsigned short u16;
typedef unsigned int u32;
typedef short s16x8 __attribute__((ext_vector_type(8)));
typedef float f32x4 __attribute__((ext_vector_type(4)));

__device__ __forceinline__ u16 f2b(float f) {
    union { float f; u32 u; } v; v.f = f;
    u32 r = v.u + 0x7FFFu + ((v.u >> 16) & 1u);
    return (u16)(r >> 16);
}

__device__ __forceinline__ u32 cvtpk(float lo, float hi) {
    u32 r;
    asm volatile("v_cvt_pk_bf16_f32 %0, %1, %2" : "=v"(r) : "v"(lo), "v"(hi));
    return r;
}

#define BAR()   asm volatile("s_barrier" ::: "memory")
#define LGKM0() asm volatile("s_waitcnt lgkmcnt(0)" ::: "memory")
#define VMW(n)  asm volatile("s_waitcnt vmcnt(" #n ")" ::: "memory")

// ---------------- fp32 -> bf16 conversion (activations) ----------------
__global__ __launch_bounds__(256) void cvt_bf16(const float* __restrict__ in,
                                                u16* __restrict__ out, int n8) {
    int i = blockIdx.x * 256 + threadIdx.x;
    if (i >= n8) return;
    const float4* p = reinterpret_cast<const float4*>(in) + (size_t)i * 2;
    float4 a = p[0], b = p[1];
    s16x8 o;
    o[0] = (short)f2b(a.x); o[1] = (short)f2b(a.y);
    o[2] = (short)f2b(a.z); o[3] = (short)f2b(a.w);
    o[4] = (short)f2b(b.x); o[5] = (short)f2b(b.y);
    o[6] = (short)f2b(b.z); o[7] = (short)f2b(b.w);
    *(reinterpret_cast<s16x8*>(out) + i) = o;
}

// all 4 weight matrices in one launch (dsts are contiguous in ws)
__global__ __launch_bounds__(256) void cvt_w4(const float* __restrict__ s0,
                                              const float* __restrict__ s1,
                                              const float* __restrict__ s2,
                                              const float* __restrict__ s3,
                                              u16* __restrict__ out) {
    int i = blockIdx.x * 256 + threadIdx.x;          // i in [0, 4*524288)
    const int seg = i >> 19, li = i & 524287;
    const float* s = (seg == 0) ? s0 : (seg == 1) ? s1 : (seg == 2) ? s2 : s3;
    const float4* p = reinterpret_cast<const float4*>(s) + (size_t)li * 2;
    float4 a = p[0], b = p[1];
    s16x8 o;
    o[0] = (short)f2b(a.x); o[1] = (short)f2b(a.y);
    o[2] = (short)f2b(a.z); o[3] = (short)f2b(a.w);
    o[4] = (short)f2b(b.x); o[5] = (short)f2b(b.y);
    o[6] = (short)f2b(b.z); o[7] = (short)f2b(b.w);
    *(reinterpret_cast<s16x8*>(out) + i) = o;
}

// ---------------- 256x256 8-phase NT GEMM: C = alpha * A[M,K] @ B[N,K]^T ----------------
// OUT_MODE: 0 = bf16 row-major C[M,N]; 1 = f32 row-major.
template<int OUT_MODE>
__global__ __launch_bounds__(512, 1) void gemm256(const u16* __restrict__ Ab,
                                                  const u16* __restrict__ Bw,
                                                  void* __restrict__ Cv,
                                                  int M, int N, int K, float alpha) {
    __shared__ u16 lds[2][2][256 * 64];
    const int t = threadIdx.x, lane = t & 63, w = t >> 6;
    const int wm = w >> 2, wn = w & 3;
    const int lr = lane & 15, lk = lane >> 4;
    const int NT = K >> 6;

    // bijective XCD swizzle (gridDim.x % 8 == 0 for all launches here)
    const int ntile = N >> 8;
    int flat = blockIdx.x;
    int cpx = gridDim.x >> 3;
    int rmap = (flat & 7) * cpx + (flat >> 3);
    const int m0 = (rmap / ntile) * 256, n0 = (rmap % ntile) * 256;

    // staging constants: thread covers row q*64 + (t>>3), position chunk t&7
    const int srow = t >> 3;
    const int spos = t & 7;
    const int scon = spos ^ (srow & 7);   // content chunk (pre-swizzled source)

    auto stage = [&](const u16* gbase, int grow0, int ldsT, int buf, int q, int kt) {
        const u16* src = gbase + (size_t)(grow0 + q * 64 + srow) * K + kt * 64 + scon * 8;
        u16* dst = &lds[buf][ldsT][(q * 64 + srow) * 64 + spos * 8];
        __builtin_amdgcn_global_load_lds(
            (const __attribute__((address_space(1))) void*)src,
            (__attribute__((address_space(3))) void*)dst, 16, 0, 0);
    };

    f32x4 acc[8][4];
#pragma unroll
    for (int i = 0; i < 8; ++i)
#pragma unroll
        for (int j = 0; j < 4; ++j) acc[i][j] = {0.f, 0.f, 0.f, 0.f};

    s16x8 a[4][2], b[4][2];

    // prologue: tile 0, order BQ0-3, AQ0, AQ2, AQ1, AQ3 (A-upper last)
    stage(Bw, n0, 1, 0, 0, 0);
    stage(Bw, n0, 1, 0, 1, 0);
    stage(Bw, n0, 1, 0, 2, 0);
    stage(Bw, n0, 1, 0, 3, 0);
    stage(Ab, m0, 0, 0, 0, 0);
    stage(Ab, m0, 0, 0, 2, 0);
    stage(Ab, m0, 0, 0, 1, 0);
    stage(Ab, m0, 0, 0, 3, 0);
    VMW(2);
    BAR();

#define LDFRAG(base, row, kk) \
    (*(const s16x8*)((base) + (row) * 64 + ((((kk) * 4 + lk) ^ (lr & 7)) << 3)))

#define QUAD(mh, nh)                                                                   \
    __builtin_amdgcn_s_setprio(1);                                                     \
    _Pragma("unroll")                                                                  \
    for (int mf = 0; mf < 4; ++mf)                                                     \
        _Pragma("unroll")                                                              \
        for (int nf = 0; nf < 2; ++nf)                                                 \
            _Pragma("unroll")                                                          \
            for (int kk = 0; kk < 2; ++kk)                                             \
                acc[(mh) * 4 + mf][(nh) * 2 + nf] = __builtin_amdgcn_mfma_f32_16x16x32_bf16( \
                    a[mf][kk], b[(nh) * 2 + nf][kk], acc[(mh) * 4 + mf][(nh) * 2 + nf], 0, 0, 0); \
    __builtin_amdgcn_s_setprio(0);

    for (int kt = 0; kt < NT; ++kt) {
        const int buf = kt & 1;
        const u16* la = &lds[buf][0][0];
        const u16* lb = &lds[buf][1][0];
        const int nx = kt + 1;
        const bool st = nx < NT;

        // ---- phase 0: quadrant (0,0) ----
#pragma unroll
        for (int mf = 0; mf < 4; ++mf)
#pragma unroll
            for (int kk = 0; kk < 2; ++kk)
                a[mf][kk] = LDFRAG(la, wm * 128 + mf * 16 + lr, kk);
#pragma unroll
        for (int nf = 0; nf < 2; ++nf)
#pragma unroll
            for (int kk = 0; kk < 2; ++kk)
                b[nf][kk] = LDFRAG(lb, wn * 64 + nf * 16 + lr, kk);
        if (st) { stage(Bw, n0, 1, buf ^ 1, 0, nx); stage(Bw, n0, 1, buf ^ 1, 1, nx); }
        BAR();
        LGKM0();
        QUAD(0, 0);
        BAR();

        // ---- phase 1: quadrant (0,1) ----
#pragma unroll
        for (int nf = 2; nf < 4; ++nf)
#pragma unroll
            for (int kk = 0; kk < 2; ++kk)
                b[nf][kk] = LDFRAG(lb, wn * 64 + nf * 16 + lr, kk);
        if (st) { stage(Bw, n0, 1, buf ^ 1, 2, nx); stage(Bw, n0, 1, buf ^ 1, 3, nx); }
        BAR();
        LGKM0();
        QUAD(0, 1);
        if (kt == NT - 1) { VMW(0); } else { VMW(4); }   // current tile's A-upper landed
        BAR();

        // ---- phase 2: quadrant (1,0) ----
#pragma unroll
        for (int mf = 0; mf < 4; ++mf)
#pragma unroll
            for (int kk = 0; kk < 2; ++kk)
                a[mf][kk] = LDFRAG(la, wm * 128 + 64 + mf * 16 + lr, kk);
        if (st) { stage(Ab, m0, 0, buf ^ 1, 0, nx); stage(Ab, m0, 0, buf ^ 1, 2, nx); }
        BAR();
        LGKM0();
        QUAD(1, 0);
        BAR();

        // ---- phase 3: quadrant (1,1) ----
        if (st) { stage(Ab, m0, 0, buf ^ 1, 1, nx); stage(Ab, m0, 0, buf ^ 1, 3, nx); }
        BAR();
        QUAD(1, 1);
        VMW(2);   // next tile's first 6 quarters landed
        BAR();
    }

    // epilogue: C layout col = lr, row = lk*4 + reg
#pragma unroll
    for (int i = 0; i < 8; ++i)
#pragma unroll
        for (int j = 0; j < 4; ++j) {
            int r0 = m0 + wm * 128 + (i >> 2) * 64 + (i & 3) * 16 + lk * 4;
            int c0 = n0 + wn * 64 + j * 16 + lr;
            if constexpr (OUT_MODE == 1) {
                float* C = (float*)Cv;
#pragma unroll
                for (int r = 0; r < 4; ++r) C[(size_t)(r0 + r) * N + c0] = acc[i][j][r] * alpha;
            } else {
                u16* C = (u16*)Cv;
#pragma unroll
                for (int r = 0; r < 4; ++r) C[(size_t)(r0 + r) * N + c0] = f2b(acc[i][j][r] * alpha);
            }
        }
}

// ---------------- flash attention ----------------
// Round-12 winner (293 us) with ONE surgical change: the in-loop __syncthreads
// (vmcnt(0)+lgkmcnt(0) drain) becomes LGKM0()+BAR() — counted-wait discipline.
// Soundness: per-iter VMEM order is stageK(4), loadV(2), loadMask(12); writeV's
// data-dependency on va0/va1 forces an in-order vmcnt wait that retires
// stageK+loadV BEFORE the barrier (global_load_lds LDS-writes visible);
// lgkmcnt(0) publishes writeV's ds_writes; the 12 mask loads (wave-private VGPR
// dests) legally remain in flight across the barrier and are auto-waited at
// next tile's softmax. Everything else identical to round 12.
__global__ __launch_bounds__(512, 2) void attn_kernel(
    const u16* __restrict__ Qh, const u16* __restrict__ Kh, const u16* __restrict__ Vh,
    const float* __restrict__ mask, const float* __restrict__ kpad,
    u16* __restrict__ Comb) {
    __shared__ u16 Ks[2][64 * 128];
    __shared__ u16 Vt[2][128 * 64];

    const int t = threadIdx.x, lane = t & 63, w = t >> 6;   // w: 0..7
    const int lr = lane & 15, lk = lane >> 4;

    const int g = blockIdx.x;
    const int rm = (g & 7) * 64 + (g >> 3);      // 512 % 8 == 0: bijective
    const int qb = rm & 7, h = (rm >> 3) & 15, b = rm >> 7;  // qb fast (L3-friendly)
    const int q0w = qb * 256 + w * 32;
    const size_t rowBase = (size_t)b * S_LEN;
    const u16* Kb = Kh + rowBase * D_MODEL + h * HD_DIM;
    const u16* Vb = Vh + rowBase * D_MODEL + h * HD_DIM;

    // Q fragments (B operand): q = q0w + qi*16 + lr, d = dc*32 + lk*8 + j. (scale pre-folded)
    s16x8 qf[2][4];
#pragma unroll
    for (int qi = 0; qi < 2; ++qi)
#pragma unroll
        for (int dc = 0; dc < 4; ++dc)
            qf[qi][dc] = *(const s16x8*)(Qh + (rowBase + q0w + qi * 16 + lr) * D_MODEL +
                                         h * HD_DIM + dc * 32 + lk * 8);

    f32x4 o[2][8];
#pragma unroll
    for (int qi = 0; qi < 2; ++qi)
#pragma unroll
        for (int dt = 0; dt < 8; ++dt) o[qi][dt] = {0.f, 0.f, 0.f, 0.f};
    float m_[2] = {-3e38f, -3e38f}, l_[2] = {0.f, 0.f};

    // K staging (512 threads, 2 passes of 32 rows):
    // LDS row R = p*32 + (t>>4), position chunk t&15, content chunk = (t&15) ^ (R&7)
    const int ksub = t >> 4;                          // 0..31
    const int kchunk = (t & 15) ^ (ksub & 7);         // pre-swizzled global chunk
    // V staging (512 threads, one pass: row = t>>3 covers all 64 kv rows)
    const int vrow = t >> 3;                          // 0..63
    const int vc0 = (t & 7) * 16;
    const int vodd = vrow & 1;
    const int vp = t >> 4;                            // kv-pair 0..31

    s16x8 va0, va1;

    auto stageK = [&](int kv0, int nb) {
#pragma unroll
        for (int p = 0; p < 2; ++p) {
            const u16* src = Kb + (size_t)(kv0 + p * 32 + ksub) * D_MODEL + kchunk * 8;
            __builtin_amdgcn_global_load_lds(
                (const __attribute__((address_space(1))) void*)src,
                (__attribute__((address_space(3))) void*)(&Ks[nb][p * 4096 + t * 8]), 16, 0, 0);
        }
    };
    auto loadV = [&](int kv0) {
        const u16* p0 = Vb + (size_t)(kv0 + vrow) * D_MODEL + vc0;
        va0 = *(const s16x8*)p0;
        va1 = *(const s16x8*)(p0 + 8);
    };
    auto writeV = [&](int nb) {
        union VU { s16x8 v[2]; u32 uw[8]; u16 us[16]; };
        VU A;
        A.v[0] = va0; A.v[1] = va1;
        u32 ra[4];
#pragma unroll
        for (int i = 0; i < 4; ++i)
            ra[i] = (u32)__shfl_xor((int)(vodd ? A.uw[i] : A.uw[i + 4]), 8, 64);
#pragma unroll
        for (int e = 0; e < 8; ++e) {
            int d = vc0 + vodd * 8 + e;
            int swz = ((d >> 4) ^ (d & 7)) & 7;
            u16 rau = (u16)((ra[e >> 1] >> ((e & 1) * 16)) & 0xffff);
            u16 lo1, hi1;
            if (vodd) { lo1 = rau; hi1 = A.us[8 + e]; }
            else      { lo1 = A.us[e]; hi1 = rau; }
            int c1 = (vp >> 2) ^ swz;
            *(u32*)(&Vt[nb][d * 64 + c1 * 8 + (vp & 3) * 2]) = (u32)lo1 | ((u32)hi1 << 16);
        }
    };

    // mask/kpad register prefetch (one tile ahead)
    f32x4 mreg[2][4], kreg[4];
    auto loadMask = [&](int kv0) {
#pragma unroll
        for (int qi = 0; qi < 2; ++qi) {
            const float* mrow = mask + (size_t)(q0w + qi * 16 + lr) * S_LEN + kv0;
#pragma unroll
            for (int kt = 0; kt < 4; ++kt)
                mreg[qi][kt] = *(const f32x4*)(mrow + kt * 16 + lk * 4);
        }
#pragma unroll
        for (int kt = 0; kt < 4; ++kt)
            kreg[kt] = *(const f32x4*)(kpad + b * S_LEN + kv0 + kt * 16 + lk * 4);
    };

    // prologue: stage tile 0 (full drain once)
    stageK(0, 0);
    loadV(0);
    writeV(0);
    loadMask(0);
    __syncthreads();

    const int srcA = ((lk & 1) * 32) + lr;   // lane holding lk' = (lk&1)*2
    const int srcB = srcA + 16;

    for (int i = 0; i < 32; ++i) {
        const int cur = i & 1;
        const u16* ks = &Ks[cur][0];
        const u16* vt = &Vt[cur][0];
        const int kv0 = i * 64;

        if (i < 31) { stageK(kv0 + 64, cur ^ 1); loadV(kv0 + 64); }

        // QK^T (swapped): sc[qi][kt]: lane holds S[kv=kt*16+lk*4+r][q=qi*16+lr]
        f32x4 sc[2][4];
#pragma unroll
        for (int qi = 0; qi < 2; ++qi)
#pragma unroll
            for (int kt = 0; kt < 4; ++kt) sc[qi][kt] = {0.f, 0.f, 0.f, 0.f};
        __builtin_amdgcn_s_setprio(1);
#pragma unroll
        for (int kt = 0; kt < 4; ++kt) {
            s16x8 kf[4];
#pragma unroll
            for (int dc = 0; dc < 4; ++dc)
                kf[dc] = *(const s16x8*)(&ks[(kt * 16 + lr) * 128 +
                                             (((dc * 4 + lk) ^ (lr & 7)) << 3)]);
#pragma unroll
            for (int dc = 0; dc < 4; ++dc) {
                sc[0][kt] = __builtin_amdgcn_mfma_f32_16x16x32_bf16(kf[dc], qf[0][dc], sc[0][kt], 0, 0, 0);
                sc[1][kt] = __builtin_amdgcn_mfma_f32_16x16x32_bf16(kf[dc], qf[1][dc], sc[1][kt], 0, 0, 0);
            }
        }
        __builtin_amdgcn_s_setprio(0);

        // masks (prefetched regs) + online softmax (per-lane row-local: q = lr)
        u32 lo[2][4], hi[2][4];
#pragma unroll
        for (int qi = 0; qi < 2; ++qi) {
            float s[16];
            float mx = -3e38f;
#pragma unroll
            for (int kt = 0; kt < 4; ++kt)
#pragma unroll
                for (int r = 0; r < 4; ++r) {
                    float v = sc[qi][kt][r] + mreg[qi][kt][r] + kreg[kt][r];
                    s[kt * 4 + r] = v;
                    mx = fmaxf(mx, v);
                }
            mx = fmaxf(mx, __shfl_xor(mx, 16, 64));
            mx = fmaxf(mx, __shfl_xor(mx, 32, 64));
            // defer-max (T13, THR=8): rescale only when the running max grows
            if (__any(mx > m_[qi] + 8.0f)) {
                float mn = fmaxf(m_[qi], mx);
                float fs = __expf(m_[qi] - mn);
                m_[qi] = mn;
                l_[qi] *= fs;
#pragma unroll
                for (int r = 0; r < 4; ++r) {
                    float fsb = __shfl(fs, (lane & 48) | (lk * 4 + r), 64);
#pragma unroll
                    for (int dt = 0; dt < 8; ++dt) o[qi][dt][r] *= fsb;
                }
            }
            float ls = 0.f;
#pragma unroll
            for (int e = 0; e < 16; ++e) { s[e] = __expf(s[e] - m_[qi]); ls += s[e]; }
            ls += __shfl_xor(ls, 16, 64);
            ls += __shfl_xor(ls, 32, 64);
            l_[qi] += ls;
#pragma unroll
            for (int kt = 0; kt < 4; ++kt) {
                lo[qi][kt] = cvtpk(s[kt * 4 + 0], s[kt * 4 + 1]);
                hi[qi][kt] = cvtpk(s[kt * 4 + 2], s[kt * 4 + 3]);
            }
        }

        // prefetch next tile's mask/kpad (regs free after s[] computed above)
        if (i < 31) loadMask(kv0 + 64);

        // redistribute P (C-layout) -> A-frag in-register
        s16x8 pf[2][2];
        const bool sel = (lk >> 1) & 1;
#pragma unroll
        for (int qi = 0; qi < 2; ++qi)
#pragma unroll
            for (int hh = 0; hh < 2; ++hh) {
                u32 w0a = (u32)__shfl((int)lo[qi][2 * hh], srcA, 64);
                u32 w0b = (u32)__shfl((int)lo[qi][2 * hh + 1], srcA, 64);
                u32 w1a = (u32)__shfl((int)hi[qi][2 * hh], srcA, 64);
                u32 w1b = (u32)__shfl((int)hi[qi][2 * hh + 1], srcA, 64);
                u32 w2a = (u32)__shfl((int)lo[qi][2 * hh], srcB, 64);
                u32 w2b = (u32)__shfl((int)lo[qi][2 * hh + 1], srcB, 64);
                u32 w3a = (u32)__shfl((int)hi[qi][2 * hh], srcB, 64);
                u32 w3b = (u32)__shfl((int)hi[qi][2 * hh + 1], srcB, 64);
                union { s16x8 v; u32 u[4]; } P;
                P.u[0] = sel ? w0b : w0a;
                P.u[1] = sel ? w1b : w1a;
                P.u[2] = sel ? w2b : w2a;
                P.u[3] = sel ? w3b : w3a;
                pf[qi][hh] = P.v;
            }

        // PV: o[qi][dt] += P[16x64] @ V[64x16]
        __builtin_amdgcn_s_setprio(1);
#pragma unroll
        for (int dt = 0; dt < 8; ++dt) {
            int swz = dt ^ (lr & 7);
            s16x8 vf0 = *(const s16x8*)(&vt[(dt * 16 + lr) * 64 + ((lk ^ swz) << 3)]);
            s16x8 vf1 = *(const s16x8*)(&vt[(dt * 16 + lr) * 64 + (((4 + lk) ^ swz) << 3)]);
            o[0][dt] = __builtin_amdgcn_mfma_f32_16x16x32_bf16(pf[0][0], vf0, o[0][dt], 0, 0, 0);
            o[1][dt] = __builtin_amdgcn_mfma_f32_16x16x32_bf16(pf[1][0], vf0, o[1][dt], 0, 0, 0);
            o[0][dt] = __builtin_amdgcn_mfma_f32_16x16x32_bf16(pf[0][1], vf1, o[0][dt], 0, 0, 0);
            o[1][dt] = __builtin_amdgcn_mfma_f32_16x16x32_bf16(pf[1][1], vf1, o[1][dt], 0, 0, 0);
        }
        __builtin_amdgcn_s_setprio(0);

        if (i < 31) writeV(cur ^ 1);
        // counted-wait tile barrier: writeV's va-dependency already retired this
        // tile's stageK+loadV (in-order vmcnt); publish ds_writes, keep the 12
        // mask prefetch loads in flight across the barrier.
        LGKM0();
        BAR();
    }

    // epilogue: O = o / l; o C-layout: q = qi*16 + lk*4 + r, d = dt*16 + lr
#pragma unroll
    for (int qi = 0; qi < 2; ++qi)
#pragma unroll
        for (int r = 0; r < 4; ++r) {
            float lb = __shfl(l_[qi], (lane & 48) | (lk * 4 + r), 64);
            float inv = 1.0f / lb;
            size_t row = rowBase + q0w + qi * 16 + lk * 4 + r;
            u16* dst = Comb + row * D_MODEL + h * HD_DIM + lr;
#pragma unroll
            for (int dt = 0; dt < 8; ++dt) dst[dt * 16] = f2b(o[qi][dt][r] * inv);
        }
}

extern "C" void kernel_launch(void* const* d_in, const int* in_sizes, int n_in,
                              void* d_out, int out_size, void* d_ws, size_t ws_size,
                              hipStream_t stream) {
    const float* q    = (const float*)d_in[0];
    const float* k    = (const float*)d_in[1];
    const float* v    = (const float*)d_in[2];
    const float* mask = (const float*)d_in[3];
    const float* kpad = (const float*)d_in[4];
    const float* wq   = (const float*)d_in[5];
    const float* wk   = (const float*)d_in[6];
    const float* wv   = (const float*)d_in[7];
    const float* wo   = (const float*)d_in[8];
    float* out = (float*)d_out;

    u16* wqb  = (u16*)d_ws;                 // 2048*2048 bf16 each, contiguous x4
    u16* wkb  = wqb + 4194304;
    u16* wvb  = wkb + 4194304;
    u16* wob  = wvb + 4194304;
    u16* qh   = wob + 4194304;              // 8192*2048 bf16 each
    u16* kh   = qh + 16777216;
    u16* vh   = kh + 16777216;
    u16* comb = vh + 16777216;              // doubles as activation bf16 staging
    // total: 160 MB

    const float scale = 0.08838834764831845f;  // 1/sqrt(128), folded into Q projection

    {
        int n8w = 4 * 524288;                // all 4 weight matrices, one launch
        dim3 gw((n8w + 255) / 256);
        cvt_w4<<<gw, 256, 0, stream>>>(wq, wk, wv, wo, wqb);
    }
    int n8a = 16777216 / 8;
    dim3 ga((n8a + 255) / 256);
    dim3 gg((8192 / 256) * (2048 / 256));   // 256 blocks

    cvt_bf16<<<ga, 256, 0, stream>>>(q, comb, n8a);
    gemm256<0><<<gg, 512, 0, stream>>>(comb, wqb, qh, 8192, 2048, 2048, scale);
    cvt_bf16<<<ga, 256, 0, stream>>>(k, comb, n8a);
    gemm256<0><<<gg, 512, 0, stream>>>(comb, wkb, kh, 8192, 2048, 2048, 1.0f);
    cvt_bf16<<<ga, 256, 0, stream>>>(v, comb, n8a);
    gemm256<0><<<gg, 512, 0, stream>>>(comb, wvb, vh, 8192, 2048, 2048, 1.0f);

    attn_kernel<<<dim3(512), 512, 0, stream>>>(qh, kh, vh, mask, kpad, comb);

    gemm256<1><<<gg, 512, 0, stream>>>(comb, wob, out, 8192, 2048, 2048, 1.0f);
}

// Round 14
// 575.513 us; speedup vs baseline: 2.7383x; 1.0161x over previous
//
#include <hip/hip_runtime.h>
#include <hip/hip_bf16.h>
#include <stdint.h>

#define S_LEN 2048
#define D_MODEL 2048
#define NH 16
#define HD_DIM 128
#define BATCH 4

typedef unsigned short u16;
typedef unsigned int u32;
typedef short s16x8 __attribute__((ext_vector_type(8)));
typedef float f32x4 __attribute__((ext_vector_type(4)));

__device__ __forceinline__ u16 f2b(float f) {
    union { float f; u32 u; } v; v.f = f;
    u32 r = v.u + 0x7FFFu + ((v.u >> 16) & 1u);
    return (u16)(r >> 16);
}

__device__ __forceinline__ u32 cvtpk(float lo, float hi) {
    u32 r;
    asm volatile("v_cvt_pk_bf16_f32 %0, %1, %2" : "=v"(r) : "v"(lo), "v"(hi));
    return r;
}

// pure (non-volatile) single-instruction helpers — schedulable/CSE-able
__device__ __forceinline__ float exp2a(float x) {
    float r;
    asm("v_exp_f32 %0, %1" : "=v"(r) : "v"(x));
    return r;
}
__device__ __forceinline__ float max3a(float a, float b, float c) {
    float r;
    asm("v_max3_f32 %0, %1, %2, %3" : "=v"(r) : "v"(a), "v"(b), "v"(c));
    return r;
}

#define L2E 1.4426950408889634f

#define BAR()   asm volatile("s_barrier" ::: "memory")
#define LGKM0() asm volatile("s_waitcnt lgkmcnt(0)" ::: "memory")
#define VMW(n)  asm volatile("s_waitcnt vmcnt(" #n ")" ::: "memory")

// ---------------- fp32 -> bf16 conversion (activations) ----------------
__global__ __launch_bounds__(256) void cvt_bf16(const float* __restrict__ in,
                                                u16* __restrict__ out, int n8) {
    int i = blockIdx.x * 256 + threadIdx.x;
    if (i >= n8) return;
    const float4* p = reinterpret_cast<const float4*>(in) + (size_t)i * 2;
    float4 a = p[0], b = p[1];
    s16x8 o;
    o[0] = (short)f2b(a.x); o[1] = (short)f2b(a.y);
    o[2] = (short)f2b(a.z); o[3] = (short)f2b(a.w);
    o[4] = (short)f2b(b.x); o[5] = (short)f2b(b.y);
    o[6] = (short)f2b(b.z); o[7] = (short)f2b(b.w);
    *(reinterpret_cast<s16x8*>(out) + i) = o;
}

// all 4 weight matrices in one launch (dsts are contiguous in ws)
__global__ __launch_bounds__(256) void cvt_w4(const float* __restrict__ s0,
                                              const float* __restrict__ s1,
                                              const float* __restrict__ s2,
                                              const float* __restrict__ s3,
                                              u16* __restrict__ out) {
    int i = blockIdx.x * 256 + threadIdx.x;          // i in [0, 4*524288)
    const int seg = i >> 19, li = i & 524287;
    const float* s = (seg == 0) ? s0 : (seg == 1) ? s1 : (seg == 2) ? s2 : s3;
    const float4* p = reinterpret_cast<const float4*>(s) + (size_t)li * 2;
    float4 a = p[0], b = p[1];
    s16x8 o;
    o[0] = (short)f2b(a.x); o[1] = (short)f2b(a.y);
    o[2] = (short)f2b(a.z); o[3] = (short)f2b(a.w);
    o[4] = (short)f2b(b.x); o[5] = (short)f2b(b.y);
    o[6] = (short)f2b(b.z); o[7] = (short)f2b(b.w);
    *(reinterpret_cast<s16x8*>(out) + i) = o;
}

// ---------------- 256x256 8-phase NT GEMM: C = alpha * A[M,K] @ B[N,K]^T ----------------
// OUT_MODE: 0 = bf16 row-major C[M,N]; 1 = f32 row-major.
template<int OUT_MODE>
__global__ __launch_bounds__(512, 1) void gemm256(const u16* __restrict__ Ab,
                                                  const u16* __restrict__ Bw,
                                                  void* __restrict__ Cv,
                                                  int M, int N, int K, float alpha) {
    __shared__ u16 lds[2][2][256 * 64];
    const int t = threadIdx.x, lane = t & 63, w = t >> 6;
    const int wm = w >> 2, wn = w & 3;
    const int lr = lane & 15, lk = lane >> 4;
    const int NT = K >> 6;

    // bijective XCD swizzle (gridDim.x % 8 == 0 for all launches here)
    const int ntile = N >> 8;
    int flat = blockIdx.x;
    int cpx = gridDim.x >> 3;
    int rmap = (flat & 7) * cpx + (flat >> 3);
    const int m0 = (rmap / ntile) * 256, n0 = (rmap % ntile) * 256;

    // staging constants: thread covers row q*64 + (t>>3), position chunk t&7
    const int srow = t >> 3;
    const int spos = t & 7;
    const int scon = spos ^ (srow & 7);   // content chunk (pre-swizzled source)

    auto stage = [&](const u16* gbase, int grow0, int ldsT, int buf, int q, int kt) {
        const u16* src = gbase + (size_t)(grow0 + q * 64 + srow) * K + kt * 64 + scon * 8;
        u16* dst = &lds[buf][ldsT][(q * 64 + srow) * 64 + spos * 8];
        __builtin_amdgcn_global_load_lds(
            (const __attribute__((address_space(1))) void*)src,
            (__attribute__((address_space(3))) void*)dst, 16, 0, 0);
    };

    f32x4 acc[8][4];
#pragma unroll
    for (int i = 0; i < 8; ++i)
#pragma unroll
        for (int j = 0; j < 4; ++j) acc[i][j] = {0.f, 0.f, 0.f, 0.f};

    s16x8 a[4][2], b[4][2];

    // prologue: tile 0, order BQ0-3, AQ0, AQ2, AQ1, AQ3 (A-upper last)
    stage(Bw, n0, 1, 0, 0, 0);
    stage(Bw, n0, 1, 0, 1, 0);
    stage(Bw, n0, 1, 0, 2, 0);
    stage(Bw, n0, 1, 0, 3, 0);
    stage(Ab, m0, 0, 0, 0, 0);
    stage(Ab, m0, 0, 0, 2, 0);
    stage(Ab, m0, 0, 0, 1, 0);
    stage(Ab, m0, 0, 0, 3, 0);
    VMW(2);
    BAR();

#define LDFRAG(base, row, kk) \
    (*(const s16x8*)((base) + (row) * 64 + ((((kk) * 4 + lk) ^ (lr & 7)) << 3)))

#define QUAD(mh, nh)                                                                   \
    __builtin_amdgcn_s_setprio(1);                                                     \
    _Pragma("unroll")                                                                  \
    for (int mf = 0; mf < 4; ++mf)                                                     \
        _Pragma("unroll")                                                              \
        for (int nf = 0; nf < 2; ++nf)                                                 \
            _Pragma("unroll")                                                          \
            for (int kk = 0; kk < 2; ++kk)                                             \
                acc[(mh) * 4 + mf][(nh) * 2 + nf] = __builtin_amdgcn_mfma_f32_16x16x32_bf16( \
                    a[mf][kk], b[(nh) * 2 + nf][kk], acc[(mh) * 4 + mf][(nh) * 2 + nf], 0, 0, 0); \
    __builtin_amdgcn_s_setprio(0);

    for (int kt = 0; kt < NT; ++kt) {
        const int buf = kt & 1;
        const u16* la = &lds[buf][0][0];
        const u16* lb = &lds[buf][1][0];
        const int nx = kt + 1;
        const bool st = nx < NT;

        // ---- phase 0: quadrant (0,0) ----
#pragma unroll
        for (int mf = 0; mf < 4; ++mf)
#pragma unroll
            for (int kk = 0; kk < 2; ++kk)
                a[mf][kk] = LDFRAG(la, wm * 128 + mf * 16 + lr, kk);
#pragma unroll
        for (int nf = 0; nf < 2; ++nf)
#pragma unroll
            for (int kk = 0; kk < 2; ++kk)
                b[nf][kk] = LDFRAG(lb, wn * 64 + nf * 16 + lr, kk);
        if (st) { stage(Bw, n0, 1, buf ^ 1, 0, nx); stage(Bw, n0, 1, buf ^ 1, 1, nx); }
        BAR();
        LGKM0();
        QUAD(0, 0);
        BAR();

        // ---- phase 1: quadrant (0,1) ----
#pragma unroll
        for (int nf = 2; nf < 4; ++nf)
#pragma unroll
            for (int kk = 0; kk < 2; ++kk)
                b[nf][kk] = LDFRAG(lb, wn * 64 + nf * 16 + lr, kk);
        if (st) { stage(Bw, n0, 1, buf ^ 1, 2, nx); stage(Bw, n0, 1, buf ^ 1, 3, nx); }
        BAR();
        LGKM0();
        QUAD(0, 1);
        if (kt == NT - 1) { VMW(0); } else { VMW(4); }   // current tile's A-upper landed
        BAR();

        // ---- phase 2: quadrant (1,0) ----
#pragma unroll
        for (int mf = 0; mf < 4; ++mf)
#pragma unroll
            for (int kk = 0; kk < 2; ++kk)
                a[mf][kk] = LDFRAG(la, wm * 128 + 64 + mf * 16 + lr, kk);
        if (st) { stage(Ab, m0, 0, buf ^ 1, 0, nx); stage(Ab, m0, 0, buf ^ 1, 2, nx); }
        BAR();
        LGKM0();
        QUAD(1, 0);
        BAR();

        // ---- phase 3: quadrant (1,1) ----
        if (st) { stage(Ab, m0, 0, buf ^ 1, 1, nx); stage(Ab, m0, 0, buf ^ 1, 3, nx); }
        BAR();
        QUAD(1, 1);
        VMW(2);   // next tile's first 6 quarters landed
        BAR();
    }

    // epilogue: C layout col = lr, row = lk*4 + reg
#pragma unroll
    for (int i = 0; i < 8; ++i)
#pragma unroll
        for (int j = 0; j < 4; ++j) {
            int r0 = m0 + wm * 128 + (i >> 2) * 64 + (i & 3) * 16 + lk * 4;
            int c0 = n0 + wn * 64 + j * 16 + lr;
            if constexpr (OUT_MODE == 1) {
                float* C = (float*)Cv;
#pragma unroll
                for (int r = 0; r < 4; ++r) C[(size_t)(r0 + r) * N + c0] = acc[i][j][r] * alpha;
            } else {
                u16* C = (u16*)Cv;
#pragma unroll
                for (int r = 0; r < 4; ++r) C[(size_t)(r0 + r) * N + c0] = f2b(acc[i][j][r] * alpha);
            }
        }
}

// ---------------- flash attention ----------------
// Round-13 structure (proven: 512 thr, (512,2), V dbuf LDS shfl-transpose, K dbuf
// global_load_lds, counted-wait tile barrier, defer-max, mask/kpad reg-prefetch)
// with the softmax moved to the LOG2 DOMAIN:
//  - Q-projection alpha pre-multiplied by log2(e) -> sc is already in log2 units
//  - mask/kpad folded via fma(x, log2e, acc) — same op count as the old adds
//  - exp() becomes a bare v_exp_f32 (2^x): saves 32 v_mul per tile per wave
//  - row-max via v_max3_f32 tree: 15 -> 8 ops per qi
//  - defer-max threshold 8 (e-units) -> 11.5 (log2 units); softmax is base-
//    invariant under uniform scaling, so results are mathematically identical.
__global__ __launch_bounds__(512, 2) void attn_kernel(
    const u16* __restrict__ Qh, const u16* __restrict__ Kh, const u16* __restrict__ Vh,
    const float* __restrict__ mask, const float* __restrict__ kpad,
    u16* __restrict__ Comb) {
    __shared__ u16 Ks[2][64 * 128];
    __shared__ u16 Vt[2][128 * 64];

    const int t = threadIdx.x, lane = t & 63, w = t >> 6;   // w: 0..7
    const int lr = lane & 15, lk = lane >> 4;

    const int g = blockIdx.x;
    const int rm = (g & 7) * 64 + (g >> 3);      // 512 % 8 == 0: bijective
    const int qb = rm & 7, h = (rm >> 3) & 15, b = rm >> 7;  // qb fast (L3-friendly)
    const int q0w = qb * 256 + w * 32;
    const size_t rowBase = (size_t)b * S_LEN;
    const u16* Kb = Kh + rowBase * D_MODEL + h * HD_DIM;
    const u16* Vb = Vh + rowBase * D_MODEL + h * HD_DIM;

    // Q fragments (B operand): q = q0w + qi*16 + lr, d = dc*32 + lk*8 + j.
    // (scale*log2e pre-folded into the Q projection)
    s16x8 qf[2][4];
#pragma unroll
    for (int qi = 0; qi < 2; ++qi)
#pragma unroll
        for (int dc = 0; dc < 4; ++dc)
            qf[qi][dc] = *(const s16x8*)(Qh + (rowBase + q0w + qi * 16 + lr) * D_MODEL +
                                         h * HD_DIM + dc * 32 + lk * 8);

    f32x4 o[2][8];
#pragma unroll
    for (int qi = 0; qi < 2; ++qi)
#pragma unroll
        for (int dt = 0; dt < 8; ++dt) o[qi][dt] = {0.f, 0.f, 0.f, 0.f};
    float m_[2] = {-3e38f, -3e38f}, l_[2] = {0.f, 0.f};

    // K staging (512 threads, 2 passes of 32 rows):
    // LDS row R = p*32 + (t>>4), position chunk t&15, content chunk = (t&15) ^ (R&7)
    const int ksub = t >> 4;                          // 0..31
    const int kchunk = (t & 15) ^ (ksub & 7);         // pre-swizzled global chunk
    // V staging (512 threads, one pass: row = t>>3 covers all 64 kv rows)
    const int vrow = t >> 3;                          // 0..63
    const int vc0 = (t & 7) * 16;
    const int vodd = vrow & 1;
    const int vp = t >> 4;                            // kv-pair 0..31

    s16x8 va0, va1;

    auto stageK = [&](int kv0, int nb) {
#pragma unroll
        for (int p = 0; p < 2; ++p) {
            const u16* src = Kb + (size_t)(kv0 + p * 32 + ksub) * D_MODEL + kchunk * 8;
            __builtin_amdgcn_global_load_lds(
                (const __attribute__((address_space(1))) void*)src,
                (__attribute__((address_space(3))) void*)(&Ks[nb][p * 4096 + t * 8]), 16, 0, 0);
        }
    };
    auto loadV = [&](int kv0) {
        const u16* p0 = Vb + (size_t)(kv0 + vrow) * D_MODEL + vc0;
        va0 = *(const s16x8*)p0;
        va1 = *(const s16x8*)(p0 + 8);
    };
    auto writeV = [&](int nb) {
        union VU { s16x8 v[2]; u32 uw[8]; u16 us[16]; };
        VU A;
        A.v[0] = va0; A.v[1] = va1;
        u32 ra[4];
#pragma unroll
        for (int i = 0; i < 4; ++i)
            ra[i] = (u32)__shfl_xor((int)(vodd ? A.uw[i] : A.uw[i + 4]), 8, 64);
#pragma unroll
        for (int e = 0; e < 8; ++e) {
            int d = vc0 + vodd * 8 + e;
            int swz = ((d >> 4) ^ (d & 7)) & 7;
            u16 rau = (u16)((ra[e >> 1] >> ((e & 1) * 16)) & 0xffff);
            u16 lo1, hi1;
            if (vodd) { lo1 = rau; hi1 = A.us[8 + e]; }
            else      { lo1 = A.us[e]; hi1 = rau; }
            int c1 = (vp >> 2) ^ swz;
            *(u32*)(&Vt[nb][d * 64 + c1 * 8 + (vp & 3) * 2]) = (u32)lo1 | ((u32)hi1 << 16);
        }
    };

    // mask/kpad register prefetch (one tile ahead)
    f32x4 mreg[2][4], kreg[4];
    auto loadMask = [&](int kv0) {
#pragma unroll
        for (int qi = 0; qi < 2; ++qi) {
            const float* mrow = mask + (size_t)(q0w + qi * 16 + lr) * S_LEN + kv0;
#pragma unroll
            for (int kt = 0; kt < 4; ++kt)
                mreg[qi][kt] = *(const f32x4*)(mrow + kt * 16 + lk * 4);
        }
#pragma unroll
        for (int kt = 0; kt < 4; ++kt)
            kreg[kt] = *(const f32x4*)(kpad + b * S_LEN + kv0 + kt * 16 + lk * 4);
    };

    // prologue: stage tile 0 (full drain once)
    stageK(0, 0);
    loadV(0);
    writeV(0);
    loadMask(0);
    __syncthreads();

    const int srcA = ((lk & 1) * 32) + lr;   // lane holding lk' = (lk&1)*2
    const int srcB = srcA + 16;

    for (int i = 0; i < 32; ++i) {
        const int cur = i & 1;
        const u16* ks = &Ks[cur][0];
        const u16* vt = &Vt[cur][0];
        const int kv0 = i * 64;

        if (i < 31) { stageK(kv0 + 64, cur ^ 1); loadV(kv0 + 64); }

        // QK^T (swapped): sc[qi][kt]: lane holds S[kv=kt*16+lk*4+r][q=qi*16+lr]
        f32x4 sc[2][4];
#pragma unroll
        for (int qi = 0; qi < 2; ++qi)
#pragma unroll
            for (int kt = 0; kt < 4; ++kt) sc[qi][kt] = {0.f, 0.f, 0.f, 0.f};
        __builtin_amdgcn_s_setprio(1);
#pragma unroll
        for (int kt = 0; kt < 4; ++kt) {
            s16x8 kf[4];
#pragma unroll
            for (int dc = 0; dc < 4; ++dc)
                kf[dc] = *(const s16x8*)(&ks[(kt * 16 + lr) * 128 +
                                             (((dc * 4 + lk) ^ (lr & 7)) << 3)]);
#pragma unroll
            for (int dc = 0; dc < 4; ++dc) {
                sc[0][kt] = __builtin_amdgcn_mfma_f32_16x16x32_bf16(kf[dc], qf[0][dc], sc[0][kt], 0, 0, 0);
                sc[1][kt] = __builtin_amdgcn_mfma_f32_16x16x32_bf16(kf[dc], qf[1][dc], sc[1][kt], 0, 0, 0);
            }
        }
        __builtin_amdgcn_s_setprio(0);

        // masks (prefetched regs, folded *log2e via fma) + online softmax (log2 domain)
        u32 lo[2][4], hi[2][4];
#pragma unroll
        for (int qi = 0; qi < 2; ++qi) {
            float s[16];
#pragma unroll
            for (int kt = 0; kt < 4; ++kt)
#pragma unroll
                for (int r = 0; r < 4; ++r)
                    s[kt * 4 + r] = fmaf(mreg[qi][kt][r], L2E,
                                         fmaf(kreg[kt][r], L2E, sc[qi][kt][r]));
            // row max via v_max3 tree (8 ops)
            float t0 = max3a(s[0], s[1], s[2]);
            float t1 = max3a(s[3], s[4], s[5]);
            float t2 = max3a(s[6], s[7], s[8]);
            float t3 = max3a(s[9], s[10], s[11]);
            float t4 = max3a(s[12], s[13], s[14]);
            float mx = fmaxf(max3a(t0, t1, t2), max3a(t3, t4, s[15]));
            mx = fmaxf(mx, __shfl_xor(mx, 16, 64));
            mx = fmaxf(mx, __shfl_xor(mx, 32, 64));
            // defer-max (T13): 11.5 log2-units ~= 8 e-units
            if (__any(mx > m_[qi] + 11.5f)) {
                float mn = fmaxf(m_[qi], mx);
                float fs = exp2a(m_[qi] - mn);
                m_[qi] = mn;
                l_[qi] *= fs;
#pragma unroll
                for (int r = 0; r < 4; ++r) {
                    float fsb = __shfl(fs, (lane & 48) | (lk * 4 + r), 64);
#pragma unroll
                    for (int dt = 0; dt < 8; ++dt) o[qi][dt][r] *= fsb;
                }
            }
            float ls = 0.f;
#pragma unroll
            for (int e = 0; e < 16; ++e) { s[e] = exp2a(s[e] - m_[qi]); ls += s[e]; }
            ls += __shfl_xor(ls, 16, 64);
            ls += __shfl_xor(ls, 32, 64);
            l_[qi] += ls;
#pragma unroll
            for (int kt = 0; kt < 4; ++kt) {
                lo[qi][kt] = cvtpk(s[kt * 4 + 0], s[kt * 4 + 1]);
                hi[qi][kt] = cvtpk(s[kt * 4 + 2], s[kt * 4 + 3]);
            }
        }

        // prefetch next tile's mask/kpad (regs free after s[] computed above)
        if (i < 31) loadMask(kv0 + 64);

        // redistribute P (C-layout) -> A-frag in-register
        s16x8 pf[2][2];
        const bool sel = (lk >> 1) & 1;
#pragma unroll
        for (int qi = 0; qi < 2; ++qi)
#pragma unroll
            for (int hh = 0; hh < 2; ++hh) {
                u32 w0a = (u32)__shfl((int)lo[qi][2 * hh], srcA, 64);
                u32 w0b = (u32)__shfl((int)lo[qi][2 * hh + 1], srcA, 64);
                u32 w1a = (u32)__shfl((int)hi[qi][2 * hh], srcA, 64);
                u32 w1b = (u32)__shfl((int)hi[qi][2 * hh + 1], srcA, 64);
                u32 w2a = (u32)__shfl((int)lo[qi][2 * hh], srcB, 64);
                u32 w2b = (u32)__shfl((int)lo[qi][2 * hh + 1], srcB, 64);
                u32 w3a = (u32)__shfl((int)hi[qi][2 * hh], srcB, 64);
                u32 w3b = (u32)__shfl((int)hi[qi][2 * hh + 1], srcB, 64);
                union { s16x8 v; u32 u[4]; } P;
                P.u[0] = sel ? w0b : w0a;
                P.u[1] = sel ? w1b : w1a;
                P.u[2] = sel ? w2b : w2a;
                P.u[3] = sel ? w3b : w3a;
                pf[qi][hh] = P.v;
            }

        // PV: o[qi][dt] += P[16x64] @ V[64x16]
        __builtin_amdgcn_s_setprio(1);
#pragma unroll
        for (int dt = 0; dt < 8; ++dt) {
            int swz = dt ^ (lr & 7);
            s16x8 vf0 = *(const s16x8*)(&vt[(dt * 16 + lr) * 64 + ((lk ^ swz) << 3)]);
            s16x8 vf1 = *(const s16x8*)(&vt[(dt * 16 + lr) * 64 + (((4 + lk) ^ swz) << 3)]);
            o[0][dt] = __builtin_amdgcn_mfma_f32_16x16x32_bf16(pf[0][0], vf0, o[0][dt], 0, 0, 0);
            o[1][dt] = __builtin_amdgcn_mfma_f32_16x16x32_bf16(pf[1][0], vf0, o[1][dt], 0, 0, 0);
            o[0][dt] = __builtin_amdgcn_mfma_f32_16x16x32_bf16(pf[0][1], vf1, o[0][dt], 0, 0, 0);
            o[1][dt] = __builtin_amdgcn_mfma_f32_16x16x32_bf16(pf[1][1], vf1, o[1][dt], 0, 0, 0);
        }
        __builtin_amdgcn_s_setprio(0);

        if (i < 31) writeV(cur ^ 1);
        // counted-wait tile barrier: writeV's va-dependency already retired this
        // tile's stageK+loadV (in-order vmcnt); publish ds_writes, keep the 12
        // mask prefetch loads in flight across the barrier.
        LGKM0();
        BAR();
    }

    // epilogue: O = o / l; o C-layout: q = qi*16 + lk*4 + r, d = dt*16 + lr
#pragma unroll
    for (int qi = 0; qi < 2; ++qi)
#pragma unroll
        for (int r = 0; r < 4; ++r) {
            float lb = __shfl(l_[qi], (lane & 48) | (lk * 4 + r), 64);
            float inv = 1.0f / lb;
            size_t row = rowBase + q0w + qi * 16 + lk * 4 + r;
            u16* dst = Comb + row * D_MODEL + h * HD_DIM + lr;
#pragma unroll
            for (int dt = 0; dt < 8; ++dt) dst[dt * 16] = f2b(o[qi][dt][r] * inv);
        }
}

extern "C" void kernel_launch(void* const* d_in, const int* in_sizes, int n_in,
                              void* d_out, int out_size, void* d_ws, size_t ws_size,
                              hipStream_t stream) {
    const float* q    = (const float*)d_in[0];
    const float* k    = (const float*)d_in[1];
    const float* v    = (const float*)d_in[2];
    const float* mask = (const float*)d_in[3];
    const float* kpad = (const float*)d_in[4];
    const float* wq   = (const float*)d_in[5];
    const float* wk   = (const float*)d_in[6];
    const float* wv   = (const float*)d_in[7];
    const float* wo   = (const float*)d_in[8];
    float* out = (float*)d_out;

    u16* wqb  = (u16*)d_ws;                 // 2048*2048 bf16 each, contiguous x4
    u16* wkb  = wqb + 4194304;
    u16* wvb  = wkb + 4194304;
    u16* wob  = wvb + 4194304;
    u16* qh   = wob + 4194304;              // 8192*2048 bf16 each
    u16* kh   = qh + 16777216;
    u16* vh   = kh + 16777216;
    u16* comb = vh + 16777216;              // doubles as activation bf16 staging
    // total: 160 MB

    // 1/sqrt(128) * log2(e): Q-projection alpha puts QK^T scores in log2 domain
    const float scale = 0.08838834764831845f * 1.4426950408889634f;

    {
        int n8w = 4 * 524288;                // all 4 weight matrices, one launch
        dim3 gw((n8w + 255) / 256);
        cvt_w4<<<gw, 256, 0, stream>>>(wq, wk, wv, wo, wqb);
    }
    int n8a = 16777216 / 8;
    dim3 ga((n8a + 255) / 256);
    dim3 gg((8192 / 256) * (2048 / 256));   // 256 blocks

    cvt_bf16<<<ga, 256, 0, stream>>>(q, comb, n8a);
    gemm256<0><<<gg, 512, 0, stream>>>(comb, wqb, qh, 8192, 2048, 2048, scale);
    cvt_bf16<<<ga, 256, 0, stream>>>(k, comb, n8a);
    gemm256<0><<<gg, 512, 0, stream>>>(comb, wkb, kh, 8192, 2048, 2048, 1.0f);
    cvt_bf16<<<ga, 256, 0, stream>>>(v, comb, n8a);
    gemm256<0><<<gg, 512, 0, stream>>>(comb, wvb, vh, 8192, 2048, 2048, 1.0f);

    attn_kernel<<<dim3(512), 512, 0, stream>>>(qh, kh, vh, mask, kpad, comb);

    gemm256<1><<<gg, 512, 0, stream>>>(comb, wob, out, 8192, 2048, 2048, 1.0f);
}